// Round 2
// baseline (287.745 us; speedup 1.0000x reference)
//
#include <hip/hip_runtime.h>
#include <hip/hip_cooperative_groups.h>
#include <math.h>

namespace cg = cooperative_groups;

typedef short bf16x8 __attribute__((ext_vector_type(8)));
typedef float f32x4 __attribute__((ext_vector_type(4)));

#define BDIM 256
constexpr int B_ = 2, H_ = 16, L_ = 1024, D_ = 64, LMAX_ = 2048;
constexpr int BH_ = B_ * H_;
constexpr float PI_F = 3.14159265358979323846f;

// ws float offsets
constexpr int WS_SVP = 0;                    // fp32 [2][32][16][64] SumV partials
constexpr int WS_KBR = 65536;                // u16 [32][1024][64]
constexpr int WS_KBI = WS_KBR + 1048576;
constexpr int WS_VTR = WS_KBI + 1048576;     // u16 [32][64][1024]
constexpr int WS_VTI = WS_VTR + 1048576;

__device__ __forceinline__ unsigned short f2b(float x) {
    union { float f; unsigned u; } v; v.f = x;
    return (unsigned short)((v.u + 0x8000u) >> 16);
}
__device__ __forceinline__ float b2f(unsigned short x) {
    union { unsigned u; float f; } v; v.u = ((unsigned)x) << 16;
    return v.f;
}
__device__ __forceinline__ unsigned pk2(float a, float b) {
    union { float f; unsigned u; } va, vb; va.f = a; vb.f = b;
    return ((va.u + 0x8000u) >> 16) | ((vb.u + 0x8000u) & 0xFFFF0000u);
}
__device__ __forceinline__ uint4 pack4(const float4& a, const float4& b) {
    return make_uint4(pk2(a.x, a.y), pk2(a.z, a.w), pk2(b.x, b.y), pk2(b.z, b.w));
}

#define MFMA(a, b, c) __builtin_amdgcn_mfma_f32_16x16x32_bf16((a), (b), (c), 0, 0, 0)

__device__ __forceinline__ float a_val(int s, int l, float4 invn) {
    const float fr = (s == 0) ? 1.0f : (s == 1) ? 0.5f : (s == 2) ? 0.25f : 0.1f;
    const float iv = (s == 0) ? invn.x : (s == 1) ? invn.y : (s == 2) ? invn.z : invn.w;
    float t = (2.0f * PI_F * fr / (float)(LMAX_ - 1)) * (float)l;
    float m2 = 3.0f + 2.0f * cosf(t) + 2.0f * cosf(0.5f * t) + 2.0f * cosf(1.5f * t);
    return sqrtf(fmaxf(m2, 0.0f)) * iv;
}

// Shared-memory layout: prep phase (p) aliases the first 10KB of the attn
// phase (a) buffers; sAmb (at ~64KB) is disjoint from p, so the amb table can
// be filled during phase 1 and persists into the attn body.
union SMem {
    struct {
        unsigned short sK0[2][4096], sK1[2][4096];   // K dbuf
        unsigned short sV0[4096], sV1[4096];
        unsigned short sE[4096], sMg[4096];          // stride 64: conflict-free
        unsigned short sAmb[4 * 1032];
        float sDen[4 * 64];
    } a;
    struct {
        unsigned short sT[64 * 70];                  // stride 70: see prep notes
        float sRed[4 * 64];
    } p;
};

// ---------------- helpers ----------------
__device__ __forceinline__ void stage64s(const unsigned short* g0, int stride,
                                         unsigned short* lds, int w, int lane) {
#pragma unroll
    for (int i = 0; i < 2; ++i) {
        int c = w * 2 + i;
        int lrow = c * 8 + (lane >> 3);
        int lg = (lane & 7) ^ (lrow & 7);
        const unsigned short* src = g0 + (size_t)lrow * stride + lg * 8;
        __builtin_amdgcn_global_load_lds(
            (const __attribute__((address_space(1))) void*)src,
            (__attribute__((address_space(3))) void*)(lds + c * 512), 16, 0, 0);
    }
}
__device__ __forceinline__ bf16x8 ldfrag(const unsigned short* b, int row, int g) {
    return *(const bf16x8*)&b[row * 64 + ((g ^ (row & 7)) << 3)];
}

// ---------------- V^T tile + SVp (one 64x64 tile) ----------------
__device__ __forceinline__ void vt_tile(int vb, const float* __restrict__ Vr,
                                        const float* __restrict__ Vi,
                                        float* __restrict__ ws, SMem& sm) {
    const int tid = threadIdx.x;
    const int comp = vb & 1, mt = (vb >> 1) & 15, bh = vb >> 5;
    const int m0 = mt * 64;
    unsigned short* VtR = (unsigned short*)(ws + WS_VTR);
    unsigned short* VtI = (unsigned short*)(ws + WS_VTI);
    const float* src = (comp ? Vi : Vr) + (size_t)bh * 65536 + (size_t)m0 * 64;
    unsigned short* dstA = (comp ? VtI : VtR) + (size_t)bh * 65536;
    __syncthreads();   // protect sT/sRed reuse against previous tile's readers
#pragma unroll
    for (int i = 0; i < 4; ++i) {
        int e = i * 256 + tid;
        int m = e >> 4, d4 = (e & 15) * 4;
        float4 x = *(const float4*)(src + (size_t)m * 64 + d4);
        *(uint2*)&sm.p.sT[m * 70 + d4] = make_uint2(pk2(x.x, x.y), pk2(x.z, x.w));
    }
    {   // SVp: fp32 column sums over the 64 m of this tile (L2-warm re-read)
        int d = tid & 63, grp = tid >> 6;
        float s = 0.0f;
#pragma unroll
        for (int k = 0; k < 16; ++k) s += src[(size_t)(grp * 16 + k) * 64 + d];
        sm.p.sRed[grp * 64 + d] = s;
    }
    __syncthreads();
    {   // transposed write: thread -> d = tid>>2, ms = (tid&3)*16
        int d = tid >> 2, ms = (tid & 3) * 16;
        unsigned short v[16];
#pragma unroll
        for (int k = 0; k < 16; ++k) v[k] = sm.p.sT[(ms + k) * 70 + d];
        unsigned short* dst = dstA + (size_t)d * 1024 + m0 + ms;
        *(uint4*)dst = make_uint4((unsigned)v[0] | ((unsigned)v[1] << 16),
                                  (unsigned)v[2] | ((unsigned)v[3] << 16),
                                  (unsigned)v[4] | ((unsigned)v[5] << 16),
                                  (unsigned)v[6] | ((unsigned)v[7] << 16));
        *(uint4*)(dst + 8) = make_uint4((unsigned)v[8] | ((unsigned)v[9] << 16),
                                        (unsigned)v[10] | ((unsigned)v[11] << 16),
                                        (unsigned)v[12] | ((unsigned)v[13] << 16),
                                        (unsigned)v[14] | ((unsigned)v[15] << 16));
    }
    if (tid < 64)
        ws[WS_SVP + comp * 32768 + bh * 1024 + mt * 64 + tid] =
            sm.p.sRed[tid] + sm.p.sRed[64 + tid] + sm.p.sRed[128 + tid] +
            sm.p.sRed[192 + tid];
}

// ---------------- attention body (shared by fused + fallback) ----------------
__device__ __forceinline__ void attn_body(const float* __restrict__ Qr,
                                          const float* __restrict__ Qi,
                                          const float* __restrict__ ws,
                                          float* __restrict__ out, float4 invn,
                                          SMem& sm, bool fillAmb) {
    auto& A = sm.a;
    const int tid = threadIdx.x;
    const int lane = tid & 63;
    const int w = tid >> 6;
    const int lo16 = lane & 15;
    const int quad = lane >> 4;
    const int blk = blockIdx.x;
    const int bh = (blk & 7) * 4 + (blk >> 7);   // XCD-clustered
    const int qt = (blk >> 3) & 15;
    const int l0 = qt * 64;
    const size_t base = (size_t)bh * (L_ * D_);

    const unsigned short* gKr = (const unsigned short*)(ws + WS_KBR) + (size_t)bh * 65536;
    const unsigned short* gKi = (const unsigned short*)(ws + WS_KBI) + (size_t)bh * 65536;
    const unsigned short* gVr = (const unsigned short*)(ws + WS_VTR) + (size_t)bh * 65536;
    const unsigned short* gVi = (const unsigned short*)(ws + WS_VTI) + (size_t)bh * 65536;

    // issue K(0) staging first so it overlaps amb/Q work
    stage64s(gKr, 64, A.sK0[0], w, lane);
    stage64s(gKi, 64, A.sK1[0], w, lane);

    if (fillAmb) {
        for (int e = tid; e < 4096; e += BDIM) {
            int s = e >> 10, l = e & 1023;
            A.sAmb[s * 1032 + l] = f2b(a_val(s, l, invn) * 0.125f);
        }
    }

    // Q fragments (register-resident)
    bf16x8 fQr0, fQr1, fQi0, fQi1, fnQi0, fnQi1;
    {
        const int ql = l0 + w * 16 + lo16;
        const float* qr = Qr + base + (size_t)ql * 64;
        const float* qi = Qi + base + (size_t)ql * 64;
        float4 a0 = *(const float4*)(qr + quad * 8);
        float4 a1 = *(const float4*)(qr + quad * 8 + 4);
        float4 b0 = *(const float4*)(qr + 32 + quad * 8);
        float4 b1 = *(const float4*)(qr + 32 + quad * 8 + 4);
        *(uint4*)&fQr0 = pack4(a0, a1);
        *(uint4*)&fQr1 = pack4(b0, b1);
        a0 = *(const float4*)(qi + quad * 8);
        a1 = *(const float4*)(qi + quad * 8 + 4);
        b0 = *(const float4*)(qi + 32 + quad * 8);
        b1 = *(const float4*)(qi + 32 + quad * 8 + 4);
        *(uint4*)&fQi0 = pack4(a0, a1);
        *(uint4*)&fQi1 = pack4(b0, b1);
        uint4 t0 = *(uint4*)&fQi0, t1 = *(uint4*)&fQi1;
        t0.x ^= 0x80008000u; t0.y ^= 0x80008000u; t0.z ^= 0x80008000u; t0.w ^= 0x80008000u;
        t1.x ^= 0x80008000u; t1.y ^= 0x80008000u; t1.z ^= 0x80008000u; t1.w ^= 0x80008000u;
        *(uint4*)&fnQi0 = t0; *(uint4*)&fnQi1 = t1;
    }

    f32x4 accM1 = (f32x4){0.f, 0.f, 0.f, 0.f};
    f32x4 aOutR[4], aOutI[4];
#pragma unroll
    for (int dt = 0; dt < 4; ++dt) {
        aOutR[dt] = (f32x4){0.f, 0.f, 0.f, 0.f};
        aOutI[dt] = (f32x4){0.f, 0.f, 0.f, 0.f};
    }

    __syncthreads();   // full drain: K(0) staged, sAmb visible to all waves

    // uf1a: scale s=quad, al_s[l]/1024 in k-slot 0 (rank-4 trick).
    // sAmb holds bf16(a/8); /128 is an exact exponent shift -> f2b is exact.
    bf16x8 uf1a = (bf16x8){0, 0, 0, 0, 0, 0, 0, 0};
    uf1a[0] = (short)f2b(b2f(A.sAmb[quad * 1032 + (l0 + w * 16 + lo16)]) *
                         (1.0f / 128.0f));

    int cur = 0;
#pragma unroll 1
    for (int mt = 0; mt < 16; ++mt) {
        const int m0 = mt * 64;
        // V(mt): issued now (oldest 4 vmem ops), consumed after mid barrier
        stage64s(gVr + m0, 1024, A.sV0, w, lane);
        stage64s(gVi + m0, 1024, A.sV1, w, lane);
        // K(mt+1): prefetch into the other buffer, drains at end barrier
        if (mt < 15) {
            stage64s(gKr + (size_t)(m0 + 64) * 64, 64, A.sK0[cur ^ 1], w, lane);
            stage64s(gKi + (size_t)(m0 + 64) * 64, 64, A.sK1[cur ^ 1], w, lane);
        }
        const unsigned short* cK0 = A.sK0[cur];
        const unsigned short* cK1 = A.sK1[cur];

#pragma unroll
        for (int ct = 0; ct < 4; ++ct) {
            const int mrow = ct * 16 + lo16;
            bf16x8 kr0 = ldfrag(cK0, mrow, quad), kr1 = ldfrag(cK0, mrow, quad + 4);
            bf16x8 ki0 = ldfrag(cK1, mrow, quad), ki1 = ldfrag(cK1, mrow, quad + 4);
            f32x4 aR = (f32x4){0.f, 0.f, 0.f, 0.f};
            f32x4 aI = (f32x4){0.f, 0.f, 0.f, 0.f};
            __builtin_amdgcn_s_setprio(1);
            aR = MFMA(kr0, fQr0, aR);  aR = MFMA(kr1, fQr1, aR);   // S^T = K·Q^T
            aR = MFMA(ki0, fnQi0, aR); aR = MFMA(ki1, fnQi1, aR);
            aI = MFMA(ki0, fQr0, aI);  aI = MFMA(ki1, fQr1, aI);
            aI = MFMA(kr0, fQi0, aI);  aI = MFMA(kr1, fQi1, aI);
            __builtin_amdgcn_s_setprio(0);
            float mg0 = sqrtf(fmaf(aR[0], aR[0], aI[0] * aI[0]));
            float mg1 = sqrtf(fmaf(aR[1], aR[1], aI[1] * aI[1]));
            float mg2 = sqrtf(fmaf(aR[2], aR[2], aI[2] * aI[2]));
            float mg3 = sqrtf(fmaf(aR[3], aR[3], aI[3] * aI[3]));
            // P'[l,m] = (sum_s al_s[l]·am_s[m]/1024) · mag, rank-4 MFMA
            bf16x8 bf1 = (bf16x8){0, 0, 0, 0, 0, 0, 0, 0};
            bf1[0] = (short)A.sAmb[quad * 1032 + m0 + ct * 16 + lo16];
            f32x4 z = (f32x4){0.f, 0.f, 0.f, 0.f};
            f32x4 a1 = MFMA(bf1, uf1a, z);
            float p0 = mg0 * a1[0], p1 = mg1 * a1[1];
            float p2 = mg2 * a1[2], p3 = mg3 * a1[3];
            int l = w * 16 + lo16;
            int gph = (ct * 2 + (quad >> 1)) ^ (l & 7);
            *(uint2*)&A.sE[l * 64 + gph * 8 + (quad & 1) * 4] =
                make_uint2(pk2(p0, p1), pk2(p2, p3));
            *(uint2*)&A.sMg[l * 64 + gph * 8 + (quad & 1) * 4] =
                make_uint2(pk2(mg0, mg1), pk2(mg2, mg3));
        }
        // M1 matvec for exact denominators (same-wave slab round-trip)
        {
            bf16x8 mf0 = ldfrag(A.sMg, w * 16 + lo16, quad);
            bf16x8 mf1 = ldfrag(A.sMg, w * 16 + lo16, quad + 4);
            bf16x8 b0 = (bf16x8){0, 0, 0, 0, 0, 0, 0, 0};
            bf16x8 b1 = (bf16x8){0, 0, 0, 0, 0, 0, 0, 0};
            if (lo16 < 4) {
                b0 = *(const bf16x8*)&A.sAmb[lo16 * 1032 + m0 + quad * 8];
                b1 = *(const bf16x8*)&A.sAmb[lo16 * 1032 + m0 + 32 + quad * 8];
            }
            accM1 = MFMA(mf0, b0, accM1);
            accM1 = MFMA(mf1, b1, accM1);
        }
        // V(mt) are the 4 oldest vmem ops (in-order retirement): vmcnt(4)
        // leaves the K(mt+1) prefetch in flight across the barrier.
        if (mt < 15) {
            asm volatile("s_waitcnt vmcnt(4)" ::: "memory");
        } else {
            asm volatile("s_waitcnt vmcnt(0)" ::: "memory");
        }
        __builtin_amdgcn_s_barrier();
        // PV: out += P' @ V
        {
            bf16x8 pa0 = ldfrag(A.sE, w * 16 + lo16, quad);
            bf16x8 pa1 = ldfrag(A.sE, w * 16 + lo16, quad + 4);
            __builtin_amdgcn_s_setprio(1);
#pragma unroll
            for (int dt = 0; dt < 4; ++dt) {
                int dr = dt * 16 + lo16;
                bf16x8 vr0 = ldfrag(A.sV0, dr, quad), vr1 = ldfrag(A.sV0, dr, quad + 4);
                bf16x8 vi0 = ldfrag(A.sV1, dr, quad), vi1 = ldfrag(A.sV1, dr, quad + 4);
                aOutR[dt] = MFMA(pa0, vr0, aOutR[dt]);
                aOutR[dt] = MFMA(pa1, vr1, aOutR[dt]);
                aOutI[dt] = MFMA(pa0, vi0, aOutI[dt]);
                aOutI[dt] = MFMA(pa1, vi1, aOutI[dt]);
            }
            __builtin_amdgcn_s_setprio(0);
        }
        // K(mt+1) had the whole iteration to land; all waves done reading sV
        // before the next iteration's V stage overwrites it.
        asm volatile("s_waitcnt vmcnt(0)" ::: "memory");
        __builtin_amdgcn_s_barrier();
        cur ^= 1;
    }

    // exact denominators (epilogue-only): den_s[l] = 1024 + al_s[l]·M1[l,s]
    if (lo16 < 4) {
#pragma unroll
        for (int reg = 0; reg < 4; ++reg) {
            int r = w * 16 + quad * 4 + reg;
            float alv = b2f(A.sAmb[lo16 * 1032 + (l0 + r)]) * 8.0f;
            A.sDen[lo16 * 64 + r] = 1.0f / (1024.0f + alv * accM1[reg]);
        }
    }
    float cden[4];
#pragma unroll
    for (int reg = 0; reg < 4; ++reg) {
        int r = w * 16 + quad * 4 + reg;   // same-wave LDS read
        cden[reg] = A.sDen[r] + A.sDen[64 + r] + A.sDen[128 + r] + A.sDen[192 + r];
    }

    // expert eC per output row (10-term frequency comb)
    const float cE = rsqrtf(2048.0f) * rsqrtf(24.0f);
    float eRr[4], eRi[4];
#pragma unroll
    for (int reg = 0; reg < 4; ++reg) {
        int lrow = l0 + w * 16 + quad * 4 + reg;
        float tl = (2.0f * PI_F / (float)(LMAX_ - 1)) * (float)lrow;
        float s1, c1;
        __sincosf(0.1f * tl, &s1, &c1);
        const float W[10] = {1.f, 2.f, 3.f, 3.f, 3.f, 3.f, 3.f, 3.f, 2.f, 1.f};
        float cr = c1, ci = s1;
        float er = W[0] * cr, ei = W[0] * ci;
#pragma unroll
        for (int k = 1; k < 10; ++k) {
            float nr = cr * c1 - ci * s1;
            float ni = cr * s1 + ci * c1;
            cr = nr; ci = ni;
            er = fmaf(W[k], cr, er);
            ei = fmaf(W[k], ci, ei);
        }
        eRr[reg] = er * cE;
        eRi[reg] = ei * cE;
    }

    const size_t ooff = (size_t)BH_ * L_ * D_;
#pragma unroll
    for (int dt = 0; dt < 4; ++dt) {
        int d = dt * 16 + lo16;
        float svr = 0.0f, svi = 0.0f;
#pragma unroll
        for (int q = 0; q < 16; ++q) {
            svr += ws[WS_SVP + bh * 1024 + q * 64 + d];
            svi += ws[WS_SVP + 32768 + bh * 1024 + q * 64 + d];
        }
        float sp, cp;
        __sincosf((2.0f * PI_F / 64.0f) * (float)d, &sp, &cp);
#pragma unroll
        for (int reg = 0; reg < 4; ++reg) {
            int lrow = l0 + w * 16 + quad * 4 + reg;
            float numR = fmaf(cden[reg], svr, aOutR[dt][reg]) * 0.5f;
            float numI = fmaf(cden[reg], svi, aOutI[dt][reg]) * 0.5f;
            float epr = cp * eRr[reg] - sp * eRi[reg];
            float epi = sp * eRr[reg] + cp * eRi[reg];
            size_t o = base + (size_t)lrow * 64 + d;
            out[o] = numR * epr - numI * epi;
            out[o + ooff] = numR * epi + numI * epr;
        }
    }
}

// ---------------- fused cooperative kernel ----------------
__global__ __launch_bounds__(BDIM, 2)
void fused_kernel(const float* __restrict__ Qr, const float* __restrict__ Qi,
                  const float* __restrict__ Kr, const float* __restrict__ Ki,
                  const float* __restrict__ Vr, const float* __restrict__ Vi,
                  float* __restrict__ ws, float* __restrict__ out, float4 invn) {
    __shared__ SMem sm;
    const int tid = threadIdx.x;
    const int blk = blockIdx.x;

    // --- phase 1a: K -> bf16 (4M elems over 512 blocks = 8192/block) ---
    {
        unsigned short* KbR = (unsigned short*)(ws + WS_KBR);
        unsigned short* KbI = (unsigned short*)(ws + WS_KBI);
        const int comp = blk >> 8;
        const float* src = comp ? Ki : Kr;
        unsigned short* dst = comp ? KbI : KbR;
        size_t b0 = (size_t)(blk & 255) * 8192;
#pragma unroll
        for (int i = 0; i < 2; ++i) {
            size_t e = b0 + (size_t)(i * 256 + tid) * 16;
            float4 x0 = *(const float4*)(src + e);
            float4 x1 = *(const float4*)(src + e + 4);
            float4 x2 = *(const float4*)(src + e + 8);
            float4 x3 = *(const float4*)(src + e + 12);
            *(uint4*)(dst + e) = pack4(x0, x1);
            *(uint4*)(dst + e + 8) = pack4(x2, x3);
        }
    }
    // --- phase 1b: amb table (sAmb region is disjoint from sT/sRed) ---
    for (int e = tid; e < 4096; e += BDIM) {
        int s = e >> 10, l = e & 1023;
        sm.a.sAmb[s * 1032 + l] = f2b(a_val(s, l, invn) * 0.125f);
    }
    // --- phase 1c: V^T + SVp (1024 tiles over 512 blocks = 2/block) ---
    vt_tile(blk * 2, Vr, Vi, ws, sm);
    vt_tile(blk * 2 + 1, Vr, Vi, ws, sm);

    __threadfence();
    cg::this_grid().sync();

    // --- phase 2: attention (sAmb already filled) ---
    attn_body(Qr, Qi, ws, out, invn, sm, false);
}

// ---------------- fallback two-kernel path ----------------
__global__ __launch_bounds__(BDIM)
void prep_kernel(const float* __restrict__ Kr, const float* __restrict__ Ki,
                 const float* __restrict__ Vr, const float* __restrict__ Vi,
                 float* __restrict__ ws) {
    __shared__ SMem sm;
    const int tid = threadIdx.x;
    const int blk = blockIdx.x;
    if (blk < 256) {
        unsigned short* KbR = (unsigned short*)(ws + WS_KBR);
        unsigned short* KbI = (unsigned short*)(ws + WS_KBI);
        const int comp = blk >> 7;
        const float* src = comp ? Ki : Kr;
        unsigned short* dst = comp ? KbI : KbR;
        size_t b0 = (size_t)(blk & 127) * 16384;
#pragma unroll
        for (int i = 0; i < 4; ++i) {
            size_t e = b0 + (size_t)(i * 256 + tid) * 16;
            float4 x0 = *(const float4*)(src + e);
            float4 x1 = *(const float4*)(src + e + 4);
            float4 x2 = *(const float4*)(src + e + 8);
            float4 x3 = *(const float4*)(src + e + 12);
            *(uint4*)(dst + e) = pack4(x0, x1);
            *(uint4*)(dst + e + 8) = pack4(x2, x3);
        }
    } else {
        vt_tile(blk - 256, Vr, Vi, ws, sm);
    }
}

__global__ __launch_bounds__(BDIM, 2)
void attn_kernel(const float* __restrict__ Qr, const float* __restrict__ Qi,
                 const float* __restrict__ ws, float* __restrict__ out, float4 invn) {
    __shared__ SMem sm;
    attn_body(Qr, Qi, ws, out, invn, sm, true);
}

extern "C" void kernel_launch(void* const* d_in, const int* in_sizes, int n_in,
                              void* d_out, int out_size, void* d_ws, size_t ws_size,
                              hipStream_t stream) {
    const float* Qr = (const float*)d_in[0];
    const float* Qi = (const float*)d_in[1];
    const float* Kr = (const float*)d_in[2];
    const float* Ki = (const float*)d_in[3];
    const float* Vr = (const float*)d_in[4];
    const float* Vi = (const float*)d_in[5];
    float* ws = (float*)d_ws;
    float* out = (float*)d_out;

    // pattern norms over LMAX in closed form (double)
    const double fr[4] = {1.0, 0.5, 0.25, 0.1};
    float inv[4];
    for (int s = 0; s < 4; ++s) {
        double a = 2.0 * 3.14159265358979323846 * fr[s] / (double)(LMAX_ - 1);
        double S = 3.0 * LMAX_;
        const double mul[3] = {1.0, 0.5, 1.5};
        for (int k = 0; k < 3; ++k) {
            double x = a * mul[k];
            S += 2.0 * (cos(x * 1023.5) * sin(x * 1024.0) / sin(x * 0.5));
        }
        inv[s] = (float)(1.0 / sqrt(S));
    }
    float4 invn = make_float4(inv[0], inv[1], inv[2], inv[3]);

    // single cooperative launch (512 blocks = exactly 2/CU x 256 CU);
    // falls back to the two-kernel path if the cooperative launch is rejected.
    void* args[] = {(void*)&Qr, (void*)&Qi, (void*)&Kr, (void*)&Ki,
                    (void*)&Vr, (void*)&Vi, (void*)&ws, (void*)&out, (void*)&invn};
    hipError_t err = hipLaunchCooperativeKernel(fused_kernel, dim3(512), dim3(BDIM),
                                                args, 0, stream);
    if (err != hipSuccess) {
        prep_kernel<<<1280, BDIM, 0, stream>>>(Kr, Ki, Vr, Vi, ws);
        attn_kernel<<<512, BDIM, 0, stream>>>(Qr, Qi, ws, out, invn);
    }
}

// Round 4
// 155.382 us; speedup vs baseline: 1.8519x; 1.8519x over previous
//
#include <hip/hip_runtime.h>
#include <math.h>

typedef short bf16x8 __attribute__((ext_vector_type(8)));
typedef float f32x4 __attribute__((ext_vector_type(4)));

#define BDIM 256
constexpr int B_ = 2, H_ = 16, L_ = 1024, D_ = 64, LMAX_ = 2048;
constexpr int BH_ = B_ * H_;
constexpr float PI_F = 3.14159265358979323846f;

// ws float offsets
constexpr int WS_SVP = 0;                    // fp32 [2][32][64][16] SumV partials (d-major, q-minor)
constexpr int WS_KBR = 65536;                // u16 [32][1024][64]
constexpr int WS_KBI = WS_KBR + 1048576;
constexpr int WS_VTR = WS_KBI + 1048576;     // u16 [32][64][1024]
constexpr int WS_VTI = WS_VTR + 1048576;

__device__ __forceinline__ unsigned short f2b(float x) {
    union { float f; unsigned u; } v; v.f = x;
    return (unsigned short)((v.u + 0x8000u) >> 16);
}
__device__ __forceinline__ float b2f(unsigned short x) {
    union { unsigned u; float f; } v; v.u = ((unsigned)x) << 16;
    return v.f;
}
__device__ __forceinline__ float blo(unsigned u) {   // low bf16 of dword -> f32
    union { unsigned u; float f; } v; v.u = u << 16;
    return v.f;
}
__device__ __forceinline__ float bhi(unsigned u) {   // high bf16 of dword -> f32
    union { unsigned u; float f; } v; v.u = u & 0xFFFF0000u;
    return v.f;
}
__device__ __forceinline__ unsigned pk2(float a, float b) {
    union { float f; unsigned u; } va, vb; va.f = a; vb.f = b;
    return ((va.u + 0x8000u) >> 16) | ((vb.u + 0x8000u) & 0xFFFF0000u);
}
__device__ __forceinline__ uint4 pack4(const float4& a, const float4& b) {
    return make_uint4(pk2(a.x, a.y), pk2(a.z, a.w), pk2(b.x, b.y), pk2(b.z, b.w));
}

#define MFMA(a, b, c) __builtin_amdgcn_mfma_f32_16x16x32_bf16((a), (b), (c), 0, 0, 0)

__device__ __forceinline__ float a_val(int s, int l, float4 invn) {
    const float fr = (s == 0) ? 1.0f : (s == 1) ? 0.5f : (s == 2) ? 0.25f : 0.1f;
    const float iv = (s == 0) ? invn.x : (s == 1) ? invn.y : (s == 2) ? invn.z : invn.w;
    float t = (2.0f * PI_F * fr / (float)(LMAX_ - 1)) * (float)l;
    float m2 = 3.0f + 2.0f * cosf(t) + 2.0f * cosf(0.5f * t) + 2.0f * cosf(1.5f * t);
    return sqrtf(fmaxf(m2, 0.0f)) * iv;
}

// ---------------- prep: K->bf16, V->V^T bf16, SumV partials ----------------
// 1280 blocks: [0,256) K conv; [256,1280) V^T + SVp per (bh,mt,comp) tile.
__global__ __launch_bounds__(BDIM)
void prep_kernel(const float* __restrict__ Kr, const float* __restrict__ Ki,
                 const float* __restrict__ Vr, const float* __restrict__ Vi,
                 float* __restrict__ ws) {
    const int tid = threadIdx.x;
    const int blk = blockIdx.x;
    unsigned short* KbR = (unsigned short*)(ws + WS_KBR);
    unsigned short* KbI = (unsigned short*)(ws + WS_KBI);
    unsigned short* VtR = (unsigned short*)(ws + WS_VTR);
    unsigned short* VtI = (unsigned short*)(ws + WS_VTI);

    if (blk < 256) {
        // K -> bf16: 2M elems per comp / 128 blocks = 16384 per block
        const int comp = blk >> 7;
        const float* src = comp ? Ki : Kr;
        unsigned short* dst = comp ? KbI : KbR;
        size_t b0 = (size_t)(blk & 127) * 16384;
#pragma unroll
        for (int i = 0; i < 4; ++i) {
            size_t e = b0 + (size_t)(i * 256 + tid) * 16;
            float4 x0 = *(const float4*)(src + e);
            float4 x1 = *(const float4*)(src + e + 4);
            float4 x2 = *(const float4*)(src + e + 8);
            float4 x3 = *(const float4*)(src + e + 12);
            *(uint4*)(dst + e) = pack4(x0, x1);
            *(uint4*)(dst + e + 8) = pack4(x2, x3);
        }
    } else {
        // V^T tile + SVp: vb -> (comp, mt, bh)
        // sT stride 70 shorts (35 dwords == 3 mod 32): conflict-free writes AND
        // ~2-way reads (68 = 34 dwords == 2 mod 32 was 8-way read + 2x write).
        __shared__ unsigned short sT[64 * 70];
        __shared__ float sRed[4 * 64];
        const int vb = blk - 256;
        const int comp = vb & 1, mt = (vb >> 1) & 15, bh = vb >> 5;
        const int m0 = mt * 64;
        const float* src = (comp ? Vi : Vr) + (size_t)bh * 65536 + (size_t)m0 * 64;
        unsigned short* dstA = (comp ? VtI : VtR) + (size_t)bh * 65536;
        // stage tile bf16 into LDS
#pragma unroll
        for (int i = 0; i < 4; ++i) {
            int e = i * 256 + tid;
            int m = e >> 4, d4 = (e & 15) * 4;
            float4 x = *(const float4*)(src + (size_t)m * 64 + d4);
            *(uint2*)&sT[m * 70 + d4] = make_uint2(pk2(x.x, x.y), pk2(x.z, x.w));
        }
        // SVp: fp32 column sums over the 64 m of this tile (L2-warm re-read)
        {
            int d = tid & 63, grp = tid >> 6;
            float s = 0.0f;
#pragma unroll
            for (int k = 0; k < 16; ++k) s += src[(size_t)(grp * 16 + k) * 64 + d];
            sRed[grp * 64 + d] = s;
        }
        __syncthreads();
        // transposed write: thread -> d = tid>>2, ms = (tid&3)*16
        {
            int d = tid >> 2, ms = (tid & 3) * 16;
            unsigned short v[16];
#pragma unroll
            for (int k = 0; k < 16; ++k) v[k] = sT[(ms + k) * 70 + d];
            unsigned short* dst = dstA + (size_t)d * 1024 + m0 + ms;
            *(uint4*)dst = make_uint4((unsigned)v[0] | ((unsigned)v[1] << 16),
                                      (unsigned)v[2] | ((unsigned)v[3] << 16),
                                      (unsigned)v[4] | ((unsigned)v[5] << 16),
                                      (unsigned)v[6] | ((unsigned)v[7] << 16));
            *(uint4*)(dst + 8) = make_uint4((unsigned)v[8] | ((unsigned)v[9] << 16),
                                            (unsigned)v[10] | ((unsigned)v[11] << 16),
                                            (unsigned)v[12] | ((unsigned)v[13] << 16),
                                            (unsigned)v[14] | ((unsigned)v[15] << 16));
        }
        // SVp layout [comp][bh][d][q] so attn epilogue reads are float4-able
        if (tid < 64)
            ws[WS_SVP + comp * 32768 + bh * 1024 + tid * 16 + mt] =
                sRed[tid] + sRed[64 + tid] + sRed[128 + tid] + sRed[192 + tid];
    }
}

// ---------------- attention: K+V double-buffered, 1 barrier/iter ----------------
__device__ __forceinline__ void stage64s(const unsigned short* g0, int stride,
                                         unsigned short* lds, int w, int lane) {
#pragma unroll
    for (int i = 0; i < 2; ++i) {
        int c = w * 2 + i;
        int lrow = c * 8 + (lane >> 3);
        int lg = (lane & 7) ^ (lrow & 7);
        const unsigned short* src = g0 + (size_t)lrow * stride + lg * 8;
        __builtin_amdgcn_global_load_lds(
            (const __attribute__((address_space(1))) void*)src,
            (__attribute__((address_space(3))) void*)(lds + c * 512), 16, 0, 0);
    }
}
__device__ __forceinline__ bf16x8 ldfrag(const unsigned short* b, int row, int g) {
    return *(const bf16x8*)&b[row * 64 + ((g ^ (row & 7)) << 3)];
}

__global__ __launch_bounds__(BDIM, 2)
void attn_kernel(const float* __restrict__ Qr, const float* __restrict__ Qi,
                 const float* __restrict__ ws, float* __restrict__ out, float4 invn) {
    // K AND V double-buffered: stages for tile mt+1 are issued right after the
    // iteration-top barrier (which proves all waves finished reading that slot),
    // and waited by a near-free vmcnt(0) one full iteration later. sE is
    // wave-private (each wave writes/reads only its own 16 rows), so no mid
    // barrier is needed. M1 (denominator matvec) moved to registers: in the
    // QK^T C-layout each lane holds mg for fixed l and m=quad*4+reg.
    // LDS total = 32K (Kdbuf) + 32K (Vdbuf) + 8K (sE) + 8K (sAmb) = 81920 B
    // -> exactly 2 blocks/CU at 160 KB.
    __shared__ unsigned short sK0[2][4096], sK1[2][4096];
    __shared__ unsigned short sV0[2][4096], sV1[2][4096];
    __shared__ unsigned short sE[4096];          // stride 64: conflict-free
    __shared__ unsigned short sAmb[4 * 1024];

    const int tid = threadIdx.x;
    const int lane = tid & 63;
    const int w = tid >> 6;
    const int lo16 = lane & 15;
    const int quad = lane >> 4;
    const int blk = blockIdx.x;
    const int bh = (blk & 7) * 4 + (blk >> 7);   // XCD-clustered
    const int qt = (blk >> 3) & 15;
    const int l0 = qt * 64;
    const size_t base = (size_t)bh * (L_ * D_);

    const unsigned short* gKr = (const unsigned short*)(ws + WS_KBR) + (size_t)bh * 65536;
    const unsigned short* gKi = (const unsigned short*)(ws + WS_KBI) + (size_t)bh * 65536;
    const unsigned short* gVr = (const unsigned short*)(ws + WS_VTR) + (size_t)bh * 65536;
    const unsigned short* gVi = (const unsigned short*)(ws + WS_VTI) + (size_t)bh * 65536;

    // issue tile-0 staging first so it overlaps the amb-table trig + Q packing
    stage64s(gKr, 64, sK0[0], w, lane);
    stage64s(gKi, 64, sK1[0], w, lane);
    stage64s(gVr, 1024, sV0[0], w, lane);
    stage64s(gVi, 1024, sV1[0], w, lane);

    // amb table (a/8 bf16) in LDS
    for (int e = tid; e < 4096; e += BDIM) {
        int s = e >> 10, l = e & 1023;
        sAmb[s * 1024 + l] = f2b(a_val(s, l, invn) * 0.125f);
    }

    // Q fragments (register-resident)
    bf16x8 fQr0, fQr1, fQi0, fQi1, fnQi0, fnQi1;
    {
        const int ql = l0 + w * 16 + lo16;
        const float* qr = Qr + base + (size_t)ql * 64;
        const float* qi = Qi + base + (size_t)ql * 64;
        float4 a0 = *(const float4*)(qr + quad * 8);
        float4 a1 = *(const float4*)(qr + quad * 8 + 4);
        float4 b0 = *(const float4*)(qr + 32 + quad * 8);
        float4 b1 = *(const float4*)(qr + 32 + quad * 8 + 4);
        *(uint4*)&fQr0 = pack4(a0, a1);
        *(uint4*)&fQr1 = pack4(b0, b1);
        a0 = *(const float4*)(qi + quad * 8);
        a1 = *(const float4*)(qi + quad * 8 + 4);
        b0 = *(const float4*)(qi + 32 + quad * 8);
        b1 = *(const float4*)(qi + 32 + quad * 8 + 4);
        *(uint4*)&fQi0 = pack4(a0, a1);
        *(uint4*)&fQi1 = pack4(b0, b1);
        uint4 t0 = *(uint4*)&fQi0, t1 = *(uint4*)&fQi1;
        t0.x ^= 0x80008000u; t0.y ^= 0x80008000u; t0.z ^= 0x80008000u; t0.w ^= 0x80008000u;
        t1.x ^= 0x80008000u; t1.y ^= 0x80008000u; t1.z ^= 0x80008000u; t1.w ^= 0x80008000u;
        *(uint4*)&fnQi0 = t0; *(uint4*)&fnQi1 = t1;
    }

    __syncthreads();   // sAmb visible (also drains tile-0 stages; harmless)

    // uf1a: scale s=quad, al_s[l]/1024 in k-slot 0 (rank-4 trick).
    // sAmb holds bf16(a/8); /128 is an exact exponent shift -> f2b exact.
    bf16x8 uf1a = (bf16x8){0, 0, 0, 0, 0, 0, 0, 0};
    uf1a[0] = (short)f2b(b2f(sAmb[quad * 1024 + (l0 + w * 16 + lo16)]) *
                         (1.0f / 128.0f));

    float macc[4] = {0.f, 0.f, 0.f, 0.f};   // in-register M1 partials (per s)
    f32x4 aOutR[4], aOutI[4];
#pragma unroll
    for (int dt = 0; dt < 4; ++dt) {
        aOutR[dt] = (f32x4){0.f, 0.f, 0.f, 0.f};
        aOutI[dt] = (f32x4){0.f, 0.f, 0.f, 0.f};
    }

#pragma unroll 1
    for (int mt = 0; mt < 16; ++mt) {
        const int m0 = mt * 64;
        const int cur = mt & 1;
        // tile mt was issued a full iteration ago: vmcnt(0) is near-free.
        asm volatile("s_waitcnt vmcnt(0)" ::: "memory");
        __builtin_amdgcn_s_barrier();
        // issue tile mt+1 into the other slot (safe: barrier proved all waves
        // finished reading it in iteration mt-1)
        if (mt < 15) {
            stage64s(gKr + (size_t)(m0 + 64) * 64, 64, sK0[cur ^ 1], w, lane);
            stage64s(gKi + (size_t)(m0 + 64) * 64, 64, sK1[cur ^ 1], w, lane);
            stage64s(gVr + m0 + 64, 1024, sV0[cur ^ 1], w, lane);
            stage64s(gVi + m0 + 64, 1024, sV1[cur ^ 1], w, lane);
        }
        const unsigned short* cK0 = sK0[cur];
        const unsigned short* cK1 = sK1[cur];

#pragma unroll
        for (int ct = 0; ct < 4; ++ct) {
            const int mrow = ct * 16 + lo16;
            bf16x8 kr0 = ldfrag(cK0, mrow, quad), kr1 = ldfrag(cK0, mrow, quad + 4);
            bf16x8 ki0 = ldfrag(cK1, mrow, quad), ki1 = ldfrag(cK1, mrow, quad + 4);
            f32x4 aR = (f32x4){0.f, 0.f, 0.f, 0.f};
            f32x4 aI = (f32x4){0.f, 0.f, 0.f, 0.f};
            __builtin_amdgcn_s_setprio(1);
            aR = MFMA(kr0, fQr0, aR);  aR = MFMA(kr1, fQr1, aR);   // S^T = K·Q^T
            aR = MFMA(ki0, fnQi0, aR); aR = MFMA(ki1, fnQi1, aR);
            aI = MFMA(ki0, fQr0, aI);  aI = MFMA(ki1, fQr1, aI);
            aI = MFMA(kr0, fQi0, aI);  aI = MFMA(kr1, fQi1, aI);
            __builtin_amdgcn_s_setprio(0);
            float mg0 = sqrtf(fmaf(aR[0], aR[0], aI[0] * aI[0]));
            float mg1 = sqrtf(fmaf(aR[1], aR[1], aI[1] * aI[1]));
            float mg2 = sqrtf(fmaf(aR[2], aR[2], aI[2] * aI[2]));
            float mg3 = sqrtf(fmaf(aR[3], aR[3], aI[3] * aI[3]));
            // in-register M1: macc[s] += sum_r mg_r * amb_s[m0+ct*16+quad*4+r]
#pragma unroll
            for (int s = 0; s < 4; ++s) {
                uint2 av = *(const uint2*)&sAmb[s * 1024 + m0 + ct * 16 + quad * 4];
                macc[s] = fmaf(mg0, blo(av.x),
                          fmaf(mg1, bhi(av.x),
                          fmaf(mg2, blo(av.y),
                          fmaf(mg3, bhi(av.y), macc[s]))));
            }
            // P'[l,m] = (sum_s al_s[l]·am_s[m]/1024) · mag, rank-4 MFMA
            bf16x8 bf1 = (bf16x8){0, 0, 0, 0, 0, 0, 0, 0};
            bf1[0] = (short)sAmb[quad * 1024 + m0 + ct * 16 + lo16];
            f32x4 z = (f32x4){0.f, 0.f, 0.f, 0.f};
            f32x4 a1 = MFMA(bf1, uf1a, z);
            float p0 = mg0 * a1[0], p1 = mg1 * a1[1];
            float p2 = mg2 * a1[2], p3 = mg3 * a1[3];
            int l = w * 16 + lo16;
            int gph = (ct * 2 + (quad >> 1)) ^ (l & 7);
            *(uint2*)&sE[l * 64 + gph * 8 + (quad & 1) * 4] =
                make_uint2(pk2(p0, p1), pk2(p2, p3));
        }
        // PV: out += P' @ V  (sE wave-private; compiler orders ds_write->ds_read)
        {
            bf16x8 pa0 = ldfrag(sE, w * 16 + lo16, quad);
            bf16x8 pa1 = ldfrag(sE, w * 16 + lo16, quad + 4);
            __builtin_amdgcn_s_setprio(1);
#pragma unroll
            for (int dt = 0; dt < 4; ++dt) {
                int dr = dt * 16 + lo16;
                bf16x8 vr0 = ldfrag(sV0[cur], dr, quad), vr1 = ldfrag(sV0[cur], dr, quad + 4);
                bf16x8 vi0 = ldfrag(sV1[cur], dr, quad), vi1 = ldfrag(sV1[cur], dr, quad + 4);
                aOutR[dt] = MFMA(pa0, vr0, aOutR[dt]);
                aOutR[dt] = MFMA(pa1, vr1, aOutR[dt]);
                aOutI[dt] = MFMA(pa0, vi0, aOutI[dt]);
                aOutI[dt] = MFMA(pa1, vi1, aOutI[dt]);
            }
            __builtin_amdgcn_s_setprio(0);
        }
    }

    // ---- epilogue (all register/LDS-read only; no barrier needed) ----
    // reduce M1 partials across quad (lanes l, l+16, l+32, l+48 share l)
#pragma unroll
    for (int s = 0; s < 4; ++s) {
        macc[s] += __shfl_xor(macc[s], 16);
        macc[s] += __shfl_xor(macc[s], 32);
    }
    // per-lane combined denominator for l = l0 + w*16 + lo16
    float cden = 0.0f;
#pragma unroll
    for (int s = 0; s < 4; ++s) {
        float alv = b2f(sAmb[s * 1024 + (l0 + w * 16 + lo16)]) * 8.0f;
        cden += 1.0f / (1024.0f + alv * macc[s]);
    }
    // redistribute to output-row layout r = quad*4+reg (shfl from lane r)
    float cdenR[4];
#pragma unroll
    for (int reg = 0; reg < 4; ++reg)
        cdenR[reg] = __shfl(cden, quad * 4 + reg);

    // expert eC per output row (10-term frequency comb)
    const float cE = rsqrtf(2048.0f) * rsqrtf(24.0f);
    float eRr[4], eRi[4];
#pragma unroll
    for (int reg = 0; reg < 4; ++reg) {
        int lrow = l0 + w * 16 + quad * 4 + reg;
        float tl = (2.0f * PI_F / (float)(LMAX_ - 1)) * (float)lrow;
        float s1, c1;
        __sincosf(0.1f * tl, &s1, &c1);
        const float W[10] = {1.f, 2.f, 3.f, 3.f, 3.f, 3.f, 3.f, 3.f, 2.f, 1.f};
        float cr = c1, ci = s1;
        float er = W[0] * cr, ei = W[0] * ci;
#pragma unroll
        for (int k = 1; k < 10; ++k) {
            float nr = cr * c1 - ci * s1;
            float ni = cr * s1 + ci * c1;
            cr = nr; ci = ni;
            er = fmaf(W[k], cr, er);
            ei = fmaf(W[k], ci, ei);
        }
        eRr[reg] = er * cE;
        eRi[reg] = ei * cE;
    }

    const size_t ooff = (size_t)BH_ * L_ * D_;
#pragma unroll
    for (int dt = 0; dt < 4; ++dt) {
        int d = dt * 16 + lo16;
        // SVp now [comp][bh][d][q]: 16 consecutive floats per d -> float4 loads
        const float* svp = ws + WS_SVP + bh * 1024 + (size_t)d * 16;
        float4 r0 = *(const float4*)(svp);
        float4 r1 = *(const float4*)(svp + 4);
        float4 r2 = *(const float4*)(svp + 8);
        float4 r3 = *(const float4*)(svp + 12);
        float svr = (r0.x + r0.y + r0.z + r0.w) + (r1.x + r1.y + r1.z + r1.w) +
                    (r2.x + r2.y + r2.z + r2.w) + (r3.x + r3.y + r3.z + r3.w);
        const float* svq = svp + 32768;
        r0 = *(const float4*)(svq);
        r1 = *(const float4*)(svq + 4);
        r2 = *(const float4*)(svq + 8);
        r3 = *(const float4*)(svq + 12);
        float svi = (r0.x + r0.y + r0.z + r0.w) + (r1.x + r1.y + r1.z + r1.w) +
                    (r2.x + r2.y + r2.z + r2.w) + (r3.x + r3.y + r3.z + r3.w);
        float sp, cp;
        __sincosf((2.0f * PI_F / 64.0f) * (float)d, &sp, &cp);
#pragma unroll
        for (int reg = 0; reg < 4; ++reg) {
            int lrow = l0 + w * 16 + quad * 4 + reg;
            float numR = fmaf(cdenR[reg], svr, aOutR[dt][reg]) * 0.5f;
            float numI = fmaf(cdenR[reg], svi, aOutI[dt][reg]) * 0.5f;
            float epr = cp * eRr[reg] - sp * eRi[reg];
            float epi = sp * eRr[reg] + cp * eRi[reg];
            size_t o = base + (size_t)lrow * 64 + d;
            out[o] = numR * epr - numI * epi;
            out[o + ooff] = numR * epi + numI * epr;
        }
    }
}

extern "C" void kernel_launch(void* const* d_in, const int* in_sizes, int n_in,
                              void* d_out, int out_size, void* d_ws, size_t ws_size,
                              hipStream_t stream) {
    const float* Qr = (const float*)d_in[0];
    const float* Qi = (const float*)d_in[1];
    const float* Kr = (const float*)d_in[2];
    const float* Ki = (const float*)d_in[3];
    const float* Vr = (const float*)d_in[4];
    const float* Vi = (const float*)d_in[5];
    float* ws = (float*)d_ws;
    float* out = (float*)d_out;

    // pattern norms over LMAX in closed form (double)
    const double fr[4] = {1.0, 0.5, 0.25, 0.1};
    float inv[4];
    for (int s = 0; s < 4; ++s) {
        double a = 2.0 * 3.14159265358979323846 * fr[s] / (double)(LMAX_ - 1);
        double S = 3.0 * LMAX_;
        const double mul[3] = {1.0, 0.5, 1.5};
        for (int k = 0; k < 3; ++k) {
            double x = a * mul[k];
            S += 2.0 * (cos(x * 1023.5) * sin(x * 1024.0) / sin(x * 0.5));
        }
        inv[s] = (float)(1.0 / sqrt(S));
    }
    float4 invn = make_float4(inv[0], inv[1], inv[2], inv[3]);

    prep_kernel<<<1280, BDIM, 0, stream>>>(Kr, Ki, Vr, Vi, ws);
    attn_kernel<<<512, BDIM, 0, stream>>>(Qr, Qi, ws, out, invn);
}

// Round 5
// 143.778 us; speedup vs baseline: 2.0013x; 1.0807x over previous
//
#include <hip/hip_runtime.h>
#include <math.h>

typedef short bf16x8 __attribute__((ext_vector_type(8)));
typedef float f32x4 __attribute__((ext_vector_type(4)));

#define BDIM 256
constexpr int B_ = 2, H_ = 16, L_ = 1024, D_ = 64, LMAX_ = 2048;
constexpr int BH_ = B_ * H_;
constexpr float PI_F = 3.14159265358979323846f;

// ws float offsets
constexpr int WS_SVP = 0;                    // fp32 [2][32][64][16] SumV partials ([d][q])
constexpr int WS_KBR = 65536;                // u16 [32][1024][64]
constexpr int WS_KBI = WS_KBR + 1048576;
constexpr int WS_VTR = WS_KBI + 1048576;     // u16 [32][64][1024]
constexpr int WS_VTI = WS_VTR + 1048576;

__device__ __forceinline__ unsigned short f2b(float x) {
    union { float f; unsigned u; } v; v.f = x;
    return (unsigned short)((v.u + 0x8000u) >> 16);
}
__device__ __forceinline__ float b2f(unsigned short x) {
    union { unsigned u; float f; } v; v.u = ((unsigned)x) << 16;
    return v.f;
}
__device__ __forceinline__ unsigned pk2(float a, float b) {
    union { float f; unsigned u; } va, vb; va.f = a; vb.f = b;
    return ((va.u + 0x8000u) >> 16) | ((vb.u + 0x8000u) & 0xFFFF0000u);
}
__device__ __forceinline__ uint4 pack4(const float4& a, const float4& b) {
    return make_uint4(pk2(a.x, a.y), pk2(a.z, a.w), pk2(b.x, b.y), pk2(b.z, b.w));
}
// hot-loop f32->bf16x2 pack: 1 instr vs pk2's 5
__device__ __forceinline__ unsigned cvtpk(float lo, float hi) {
    unsigned r;
    asm("v_cvt_pk_bf16_f32 %0, %1, %2" : "=v"(r) : "v"(lo), "v"(hi));
    return r;
}
// raw v_sqrt_f32 (skip libm fixup sequence; ~1 ulp fine at bf16 precision)
__device__ __forceinline__ float vsqrt(float x) {
    float r;
    asm("v_sqrt_f32 %0, %1" : "=v"(r) : "v"(x));
    return r;
}

#define MFMA(a, b, c) __builtin_amdgcn_mfma_f32_16x16x32_bf16((a), (b), (c), 0, 0, 0)

__device__ __forceinline__ float a_val(int s, int l, float4 invn) {
    const float fr = (s == 0) ? 1.0f : (s == 1) ? 0.5f : (s == 2) ? 0.25f : 0.1f;
    const float iv = (s == 0) ? invn.x : (s == 1) ? invn.y : (s == 2) ? invn.z : invn.w;
    float t = (2.0f * PI_F * fr / (float)(LMAX_ - 1)) * (float)l;
    float m2 = 3.0f + 2.0f * cosf(t) + 2.0f * cosf(0.5f * t) + 2.0f * cosf(1.5f * t);
    return sqrtf(fmaxf(m2, 0.0f)) * iv;
}

// ---------------- prep: K->bf16, V->V^T bf16, SumV partials ----------------
// 1280 blocks: [0,256) K conv; [256,1280) V^T + SVp per (bh,mt,comp) tile.
__global__ __launch_bounds__(BDIM)
void prep_kernel(const float* __restrict__ Kr, const float* __restrict__ Ki,
                 const float* __restrict__ Vr, const float* __restrict__ Vi,
                 float* __restrict__ ws) {
    const int tid = threadIdx.x;
    const int blk = blockIdx.x;
    unsigned short* KbR = (unsigned short*)(ws + WS_KBR);
    unsigned short* KbI = (unsigned short*)(ws + WS_KBI);
    unsigned short* VtR = (unsigned short*)(ws + WS_VTR);
    unsigned short* VtI = (unsigned short*)(ws + WS_VTI);

    if (blk < 256) {
        // K -> bf16: 2M elems per comp / 128 blocks = 16384 per block
        const int comp = blk >> 7;
        const float* src = comp ? Ki : Kr;
        unsigned short* dst = comp ? KbI : KbR;
        size_t b0 = (size_t)(blk & 127) * 16384;
#pragma unroll
        for (int i = 0; i < 4; ++i) {
            size_t e = b0 + (size_t)(i * 256 + tid) * 16;
            float4 x0 = *(const float4*)(src + e);
            float4 x1 = *(const float4*)(src + e + 4);
            float4 x2 = *(const float4*)(src + e + 8);
            float4 x3 = *(const float4*)(src + e + 12);
            *(uint4*)(dst + e) = pack4(x0, x1);
            *(uint4*)(dst + e + 8) = pack4(x2, x3);
        }
    } else {
        // V^T tile + SVp: vb -> (comp, mt, bh)
        // sT stride 70 shorts (35 dwords == 3 mod 32): conflict-free writes AND
        // ~2-way reads (68 = 34 dwords == 2 mod 32 was 8-way read + 2x write).
        __shared__ unsigned short sT[64 * 70];
        __shared__ float sRed[4 * 64];
        const int vb = blk - 256;
        const int comp = vb & 1, mt = (vb >> 1) & 15, bh = vb >> 5;
        const int m0 = mt * 64;
        const float* src = (comp ? Vi : Vr) + (size_t)bh * 65536 + (size_t)m0 * 64;
        unsigned short* dstA = (comp ? VtI : VtR) + (size_t)bh * 65536;
        // stage tile bf16 into LDS
#pragma unroll
        for (int i = 0; i < 4; ++i) {
            int e = i * 256 + tid;
            int m = e >> 4, d4 = (e & 15) * 4;
            float4 x = *(const float4*)(src + (size_t)m * 64 + d4);
            *(uint2*)&sT[m * 70 + d4] = make_uint2(pk2(x.x, x.y), pk2(x.z, x.w));
        }
        // SVp: fp32 column sums over the 64 m of this tile (L2-warm re-read)
        {
            int d = tid & 63, grp = tid >> 6;
            float s = 0.0f;
#pragma unroll
            for (int k = 0; k < 16; ++k) s += src[(size_t)(grp * 16 + k) * 64 + d];
            sRed[grp * 64 + d] = s;
        }
        __syncthreads();
        // transposed write: thread -> d = tid>>2, ms = (tid&3)*16
        {
            int d = tid >> 2, ms = (tid & 3) * 16;
            unsigned short v[16];
#pragma unroll
            for (int k = 0; k < 16; ++k) v[k] = sT[(ms + k) * 70 + d];
            unsigned short* dst = dstA + (size_t)d * 1024 + m0 + ms;
            *(uint4*)dst = make_uint4((unsigned)v[0] | ((unsigned)v[1] << 16),
                                      (unsigned)v[2] | ((unsigned)v[3] << 16),
                                      (unsigned)v[4] | ((unsigned)v[5] << 16),
                                      (unsigned)v[6] | ((unsigned)v[7] << 16));
            *(uint4*)(dst + 8) = make_uint4((unsigned)v[8] | ((unsigned)v[9] << 16),
                                            (unsigned)v[10] | ((unsigned)v[11] << 16),
                                            (unsigned)v[12] | ((unsigned)v[13] << 16),
                                            (unsigned)v[14] | ((unsigned)v[15] << 16));
        }
        // SVp layout [comp][bh][d][q] so attn epilogue reads are float4-able
        if (tid < 64)
            ws[WS_SVP + comp * 32768 + bh * 1024 + tid * 16 + mt] =
                sRed[tid] + sRed[64 + tid] + sRed[128 + tid] + sRed[192 + tid];
    }
}

// ---------------- attention: round-1 structure (2 barriers, split waits) ----------------
__device__ __forceinline__ void stage64s(const unsigned short* g0, int stride,
                                         unsigned short* lds, int w, int lane) {
#pragma unroll
    for (int i = 0; i < 2; ++i) {
        int c = w * 2 + i;
        int lrow = c * 8 + (lane >> 3);
        int lg = (lane & 7) ^ (lrow & 7);
        const unsigned short* src = g0 + (size_t)lrow * stride + lg * 8;
        __builtin_amdgcn_global_load_lds(
            (const __attribute__((address_space(1))) void*)src,
            (__attribute__((address_space(3))) void*)(lds + c * 512), 16, 0, 0);
    }
}
__device__ __forceinline__ bf16x8 ldfrag(const unsigned short* b, int row, int g) {
    return *(const bf16x8*)&b[row * 64 + ((g ^ (row & 7)) << 3)];
}

__global__ __launch_bounds__(BDIM, 2)
void attn_kernel(const float* __restrict__ Qr, const float* __restrict__ Qi,
                 const float* __restrict__ ws, float* __restrict__ out, float4 invn) {
    // K double-buffered; V single-buffered (load rides under QK^T, consumed
    // after the mid barrier). Two barriers + split waits per iteration:
    // vmcnt(4) for V mid-iter, vmcnt(0) for K-prefetch at iter end.
    // (Round-4's single-barrier full-drain variant measured +17 us: full
    // drain per rendezvous absorbs the whole DMA tail; do not restructure.)
    __shared__ unsigned short sK0[2][4096], sK1[2][4096];
    __shared__ unsigned short sV0[4096], sV1[4096];
    __shared__ unsigned short sE[4096];      // stride 64: conflict-free
    __shared__ unsigned short sMg[4096];
    __shared__ unsigned short sAmb[4 * 1032];  // stride 1032: quad-spread banks
    __shared__ float sDen[4 * 64];

    const int tid = threadIdx.x;
    const int lane = tid & 63;
    const int w = tid >> 6;
    const int lo16 = lane & 15;
    const int quad = lane >> 4;
    const int blk = blockIdx.x;
    const int bh = (blk & 7) * 4 + (blk >> 7);   // XCD-clustered
    const int qt = (blk >> 3) & 15;
    const int l0 = qt * 64;
    const size_t base = (size_t)bh * (L_ * D_);

    const unsigned short* gKr = (const unsigned short*)(ws + WS_KBR) + (size_t)bh * 65536;
    const unsigned short* gKi = (const unsigned short*)(ws + WS_KBI) + (size_t)bh * 65536;
    const unsigned short* gVr = (const unsigned short*)(ws + WS_VTR) + (size_t)bh * 65536;
    const unsigned short* gVi = (const unsigned short*)(ws + WS_VTI) + (size_t)bh * 65536;

    // issue K(0) staging first so it overlaps the amb-table trig + Q packing
    stage64s(gKr, 64, sK0[0], w, lane);
    stage64s(gKi, 64, sK1[0], w, lane);

    // amb table (a/8 bf16) in LDS
    for (int e = tid; e < 4096; e += BDIM) {
        int s = e >> 10, l = e & 1023;
        sAmb[s * 1032 + l] = f2b(a_val(s, l, invn) * 0.125f);
    }

    // Q fragments (register-resident)
    bf16x8 fQr0, fQr1, fQi0, fQi1, fnQi0, fnQi1;
    {
        const int ql = l0 + w * 16 + lo16;
        const float* qr = Qr + base + (size_t)ql * 64;
        const float* qi = Qi + base + (size_t)ql * 64;
        float4 a0 = *(const float4*)(qr + quad * 8);
        float4 a1 = *(const float4*)(qr + quad * 8 + 4);
        float4 b0 = *(const float4*)(qr + 32 + quad * 8);
        float4 b1 = *(const float4*)(qr + 32 + quad * 8 + 4);
        *(uint4*)&fQr0 = pack4(a0, a1);
        *(uint4*)&fQr1 = pack4(b0, b1);
        a0 = *(const float4*)(qi + quad * 8);
        a1 = *(const float4*)(qi + quad * 8 + 4);
        b0 = *(const float4*)(qi + 32 + quad * 8);
        b1 = *(const float4*)(qi + 32 + quad * 8 + 4);
        *(uint4*)&fQi0 = pack4(a0, a1);
        *(uint4*)&fQi1 = pack4(b0, b1);
        uint4 t0 = *(uint4*)&fQi0, t1 = *(uint4*)&fQi1;
        t0.x ^= 0x80008000u; t0.y ^= 0x80008000u; t0.z ^= 0x80008000u; t0.w ^= 0x80008000u;
        t1.x ^= 0x80008000u; t1.y ^= 0x80008000u; t1.z ^= 0x80008000u; t1.w ^= 0x80008000u;
        *(uint4*)&fnQi0 = t0; *(uint4*)&fnQi1 = t1;
    }

    __syncthreads();   // sAmb visible to all waves (also drains K(0); harmless)

    // uf1a: scale s=quad, al_s[l]/1024 in k-slot 0 (rank-4 trick).
    // sAmb holds bf16(a/8); /128 is an exact exponent shift -> f2b exact.
    bf16x8 uf1a = (bf16x8){0, 0, 0, 0, 0, 0, 0, 0};
    uf1a[0] = (short)f2b(b2f(sAmb[quad * 1032 + (l0 + w * 16 + lo16)]) *
                         (1.0f / 128.0f));

    f32x4 accM1 = (f32x4){0.f, 0.f, 0.f, 0.f};
    f32x4 aOutR[4], aOutI[4];
#pragma unroll
    for (int dt = 0; dt < 4; ++dt) {
        aOutR[dt] = (f32x4){0.f, 0.f, 0.f, 0.f};
        aOutI[dt] = (f32x4){0.f, 0.f, 0.f, 0.f};
    }

#pragma unroll 1
    for (int mt = 0; mt < 16; ++mt) {
        const int m0 = mt * 64;
        const int cur = mt & 1;
        // V(mt): issued now (oldest 4 vmem ops), consumed after mid barrier
        stage64s(gVr + m0, 1024, sV0, w, lane);
        stage64s(gVi + m0, 1024, sV1, w, lane);
        // K(mt+1): prefetch into the other buffer, drains at end barrier
        if (mt < 15) {
            stage64s(gKr + (size_t)(m0 + 64) * 64, 64, sK0[cur ^ 1], w, lane);
            stage64s(gKi + (size_t)(m0 + 64) * 64, 64, sK1[cur ^ 1], w, lane);
        }
        const unsigned short* cK0 = sK0[cur];
        const unsigned short* cK1 = sK1[cur];

#pragma unroll
        for (int ct = 0; ct < 4; ++ct) {
            const int mrow = ct * 16 + lo16;
            bf16x8 kr0 = ldfrag(cK0, mrow, quad), kr1 = ldfrag(cK0, mrow, quad + 4);
            bf16x8 ki0 = ldfrag(cK1, mrow, quad), ki1 = ldfrag(cK1, mrow, quad + 4);
            f32x4 aR = (f32x4){0.f, 0.f, 0.f, 0.f};
            f32x4 aI = (f32x4){0.f, 0.f, 0.f, 0.f};
            __builtin_amdgcn_s_setprio(1);
            aR = MFMA(kr0, fQr0, aR);  aR = MFMA(kr1, fQr1, aR);   // S^T = K·Q^T
            aR = MFMA(ki0, fnQi0, aR); aR = MFMA(ki1, fnQi1, aR);
            aI = MFMA(ki0, fQr0, aI);  aI = MFMA(ki1, fQr1, aI);
            aI = MFMA(kr0, fQi0, aI);  aI = MFMA(kr1, fQi1, aI);
            __builtin_amdgcn_s_setprio(0);
            float mg0 = vsqrt(fmaf(aR[0], aR[0], aI[0] * aI[0]));
            float mg1 = vsqrt(fmaf(aR[1], aR[1], aI[1] * aI[1]));
            float mg2 = vsqrt(fmaf(aR[2], aR[2], aI[2] * aI[2]));
            float mg3 = vsqrt(fmaf(aR[3], aR[3], aI[3] * aI[3]));
            // P'[l,m] = (sum_s al_s[l]·am_s[m]/1024) · mag, rank-4 MFMA
            bf16x8 bf1 = (bf16x8){0, 0, 0, 0, 0, 0, 0, 0};
            bf1[0] = (short)sAmb[quad * 1032 + m0 + ct * 16 + lo16];
            f32x4 z = (f32x4){0.f, 0.f, 0.f, 0.f};
            f32x4 a1 = MFMA(bf1, uf1a, z);
            float p0 = mg0 * a1[0], p1 = mg1 * a1[1];
            float p2 = mg2 * a1[2], p3 = mg3 * a1[3];
            int l = w * 16 + lo16;
            int gph = (ct * 2 + (quad >> 1)) ^ (l & 7);
            *(uint2*)&sE[l * 64 + gph * 8 + (quad & 1) * 4] =
                make_uint2(cvtpk(p0, p1), cvtpk(p2, p3));
            *(uint2*)&sMg[l * 64 + gph * 8 + (quad & 1) * 4] =
                make_uint2(cvtpk(mg0, mg1), cvtpk(mg2, mg3));
        }
        // M1 matvec for exact denominators (same-wave slab round-trip)
        {
            bf16x8 mf0 = ldfrag(sMg, w * 16 + lo16, quad);
            bf16x8 mf1 = ldfrag(sMg, w * 16 + lo16, quad + 4);
            bf16x8 b0 = (bf16x8){0, 0, 0, 0, 0, 0, 0, 0};
            bf16x8 b1 = (bf16x8){0, 0, 0, 0, 0, 0, 0, 0};
            if (lo16 < 4) {
                b0 = *(const bf16x8*)&sAmb[lo16 * 1032 + m0 + quad * 8];
                b1 = *(const bf16x8*)&sAmb[lo16 * 1032 + m0 + 32 + quad * 8];
            }
            accM1 = MFMA(mf0, b0, accM1);
            accM1 = MFMA(mf1, b1, accM1);
        }
        // V(mt) are the 4 oldest vmem ops (in-order retirement): vmcnt(4)
        // leaves the K(mt+1) prefetch in flight across the barrier.
        if (mt < 15) {
            asm volatile("s_waitcnt vmcnt(4)" ::: "memory");
        } else {
            asm volatile("s_waitcnt vmcnt(0)" ::: "memory");
        }
        __builtin_amdgcn_s_barrier();
        // PV: out += P' @ V
        {
            bf16x8 pa0 = ldfrag(sE, w * 16 + lo16, quad);
            bf16x8 pa1 = ldfrag(sE, w * 16 + lo16, quad + 4);
            __builtin_amdgcn_s_setprio(1);
#pragma unroll
            for (int dt = 0; dt < 4; ++dt) {
                int dr = dt * 16 + lo16;
                bf16x8 vr0 = ldfrag(sV0, dr, quad), vr1 = ldfrag(sV0, dr, quad + 4);
                bf16x8 vi0 = ldfrag(sV1, dr, quad), vi1 = ldfrag(sV1, dr, quad + 4);
                aOutR[dt] = MFMA(pa0, vr0, aOutR[dt]);
                aOutR[dt] = MFMA(pa1, vr1, aOutR[dt]);
                aOutI[dt] = MFMA(pa0, vi0, aOutI[dt]);
                aOutI[dt] = MFMA(pa1, vi1, aOutI[dt]);
            }
            __builtin_amdgcn_s_setprio(0);
        }
        // K(mt+1) had the whole iteration to land; all waves done reading sV
        // before the next iteration's V stage overwrites it.
        asm volatile("s_waitcnt vmcnt(0)" ::: "memory");
        __builtin_amdgcn_s_barrier();
    }

    // exact denominators (epilogue-only): den_s[l] = 1024 + al_s[l]·M1[l,s]
    if (lo16 < 4) {
#pragma unroll
        for (int reg = 0; reg < 4; ++reg) {
            int r = w * 16 + quad * 4 + reg;
            float alv = b2f(sAmb[lo16 * 1032 + (l0 + r)]) * 8.0f;
            sDen[lo16 * 64 + r] = 1.0f / (1024.0f + alv * accM1[reg]);
        }
    }
    float cden[4];
#pragma unroll
    for (int reg = 0; reg < 4; ++reg) {
        int r = w * 16 + quad * 4 + reg;   // same-wave LDS read
        cden[reg] = sDen[r] + sDen[64 + r] + sDen[128 + r] + sDen[192 + r];
    }

    // expert eC per output row (10-term frequency comb)
    const float cE = rsqrtf(2048.0f) * rsqrtf(24.0f);
    float eRr[4], eRi[4];
#pragma unroll
    for (int reg = 0; reg < 4; ++reg) {
        int lrow = l0 + w * 16 + quad * 4 + reg;
        float tl = (2.0f * PI_F / (float)(LMAX_ - 1)) * (float)lrow;
        float s1, c1;
        __sincosf(0.1f * tl, &s1, &c1);
        const float W[10] = {1.f, 2.f, 3.f, 3.f, 3.f, 3.f, 3.f, 3.f, 2.f, 1.f};
        float cr = c1, ci = s1;
        float er = W[0] * cr, ei = W[0] * ci;
#pragma unroll
        for (int k = 1; k < 10; ++k) {
            float nr = cr * c1 - ci * s1;
            float ni = cr * s1 + ci * c1;
            cr = nr; ci = ni;
            er = fmaf(W[k], cr, er);
            ei = fmaf(W[k], ci, ei);
        }
        eRr[reg] = er * cE;
        eRi[reg] = ei * cE;
    }

    const size_t ooff = (size_t)BH_ * L_ * D_;
#pragma unroll
    for (int dt = 0; dt < 4; ++dt) {
        int d = dt * 16 + lo16;
        // SVp [comp][bh][d][q]: 16 consecutive floats per d -> float4 loads
        const float* svp = ws + WS_SVP + bh * 1024 + (size_t)d * 16;
        float4 r0 = *(const float4*)(svp);
        float4 r1 = *(const float4*)(svp + 4);
        float4 r2 = *(const float4*)(svp + 8);
        float4 r3 = *(const float4*)(svp + 12);
        float svr = (r0.x + r0.y + r0.z + r0.w) + (r1.x + r1.y + r1.z + r1.w) +
                    (r2.x + r2.y + r2.z + r2.w) + (r3.x + r3.y + r3.z + r3.w);
        const float* svq = svp + 32768;
        r0 = *(const float4*)(svq);
        r1 = *(const float4*)(svq + 4);
        r2 = *(const float4*)(svq + 8);
        r3 = *(const float4*)(svq + 12);
        float svi = (r0.x + r0.y + r0.z + r0.w) + (r1.x + r1.y + r1.z + r1.w) +
                    (r2.x + r2.y + r2.z + r2.w) + (r3.x + r3.y + r3.z + r3.w);
        float sp, cp;
        __sincosf((2.0f * PI_F / 64.0f) * (float)d, &sp, &cp);
#pragma unroll
        for (int reg = 0; reg < 4; ++reg) {
            int lrow = l0 + w * 16 + quad * 4 + reg;
            float numR = fmaf(cden[reg], svr, aOutR[dt][reg]) * 0.5f;
            float numI = fmaf(cden[reg], svi, aOutI[dt][reg]) * 0.5f;
            float epr = cp * eRr[reg] - sp * eRi[reg];
            float epi = sp * eRr[reg] + cp * eRi[reg];
            size_t o = base + (size_t)lrow * 64 + d;
            out[o] = numR * epr - numI * epi;
            out[o + ooff] = numR * epi + numI * epr;
        }
    }
}

extern "C" void kernel_launch(void* const* d_in, const int* in_sizes, int n_in,
                              void* d_out, int out_size, void* d_ws, size_t ws_size,
                              hipStream_t stream) {
    const float* Qr = (const float*)d_in[0];
    const float* Qi = (const float*)d_in[1];
    const float* Kr = (const float*)d_in[2];
    const float* Ki = (const float*)d_in[3];
    const float* Vr = (const float*)d_in[4];
    const float* Vi = (const float*)d_in[5];
    float* ws = (float*)d_ws;
    float* out = (float*)d_out;

    // pattern norms over LMAX in closed form (double)
    const double fr[4] = {1.0, 0.5, 0.25, 0.1};
    float inv[4];
    for (int s = 0; s < 4; ++s) {
        double a = 2.0 * 3.14159265358979323846 * fr[s] / (double)(LMAX_ - 1);
        double S = 3.0 * LMAX_;
        const double mul[3] = {1.0, 0.5, 1.5};
        for (int k = 0; k < 3; ++k) {
            double x = a * mul[k];
            S += 2.0 * (cos(x * 1023.5) * sin(x * 1024.0) / sin(x * 0.5));
        }
        inv[s] = (float)(1.0 / sqrt(S));
    }
    float4 invn = make_float4(inv[0], inv[1], inv[2], inv[3]);

    prep_kernel<<<1280, BDIM, 0, stream>>>(Kr, Ki, Vr, Vi, ws);
    attn_kernel<<<512, BDIM, 0, stream>>>(Qr, Qi, ws, out, invn);
}

// Round 6
// 136.112 us; speedup vs baseline: 2.1140x; 1.0563x over previous
//
#include <hip/hip_runtime.h>
#include <math.h>

typedef short bf16x8 __attribute__((ext_vector_type(8)));
typedef float f32x4 __attribute__((ext_vector_type(4)));

#define BDIM 256    // prep + fallback attn
#define ADIM 512    // wide attn (8 waves)
constexpr int B_ = 2, H_ = 16, L_ = 1024, D_ = 64, LMAX_ = 2048;
constexpr int BH_ = B_ * H_;
constexpr float PI_F = 3.14159265358979323846f;

// ws float offsets
constexpr int WS_SVP = 0;                    // fp32 [2][32][64][16] SumV partials ([d][q])
constexpr int WS_KBR = 65536;                // u16 [32][1024][64]
constexpr int WS_KBI = WS_KBR + 1048576;
constexpr int WS_VTR = WS_KBI + 1048576;     // u16 [32][64][1024]
constexpr int WS_VTI = WS_VTR + 1048576;

__device__ __forceinline__ unsigned short f2b(float x) {
    union { float f; unsigned u; } v; v.f = x;
    return (unsigned short)((v.u + 0x8000u) >> 16);
}
__device__ __forceinline__ float b2f(unsigned short x) {
    union { unsigned u; float f; } v; v.u = ((unsigned)x) << 16;
    return v.f;
}
__device__ __forceinline__ unsigned pk2(float a, float b) {
    union { float f; unsigned u; } va, vb; va.f = a; vb.f = b;
    return ((va.u + 0x8000u) >> 16) | ((vb.u + 0x8000u) & 0xFFFF0000u);
}
__device__ __forceinline__ uint4 pack4(const float4& a, const float4& b) {
    return make_uint4(pk2(a.x, a.y), pk2(a.z, a.w), pk2(b.x, b.y), pk2(b.z, b.w));
}
__device__ __forceinline__ unsigned cvtpk(float lo, float hi) {
    unsigned r;
    asm("v_cvt_pk_bf16_f32 %0, %1, %2" : "=v"(r) : "v"(lo), "v"(hi));
    return r;
}
__device__ __forceinline__ float vsqrt(float x) {
    float r;
    asm("v_sqrt_f32 %0, %1" : "=v"(r) : "v"(x));
    return r;
}

#define MFMA(a, b, c) __builtin_amdgcn_mfma_f32_16x16x32_bf16((a), (b), (c), 0, 0, 0)

__device__ __forceinline__ float a_val(int s, int l, float4 invn) {
    const float fr = (s == 0) ? 1.0f : (s == 1) ? 0.5f : (s == 2) ? 0.25f : 0.1f;
    const float iv = (s == 0) ? invn.x : (s == 1) ? invn.y : (s == 2) ? invn.z : invn.w;
    float t = (2.0f * PI_F * fr / (float)(LMAX_ - 1)) * (float)l;
    float m2 = 3.0f + 2.0f * cosf(t) + 2.0f * cosf(0.5f * t) + 2.0f * cosf(1.5f * t);
    return sqrtf(fmaxf(m2, 0.0f)) * iv;
}

// ---------------- prep: K->bf16, V->V^T bf16, SumV partials ----------------
__global__ __launch_bounds__(BDIM)
void prep_kernel(const float* __restrict__ Kr, const float* __restrict__ Ki,
                 const float* __restrict__ Vr, const float* __restrict__ Vi,
                 float* __restrict__ ws) {
    const int tid = threadIdx.x;
    const int blk = blockIdx.x;
    unsigned short* KbR = (unsigned short*)(ws + WS_KBR);
    unsigned short* KbI = (unsigned short*)(ws + WS_KBI);
    unsigned short* VtR = (unsigned short*)(ws + WS_VTR);
    unsigned short* VtI = (unsigned short*)(ws + WS_VTI);

    if (blk < 256) {
        const int comp = blk >> 7;
        const float* src = comp ? Ki : Kr;
        unsigned short* dst = comp ? KbI : KbR;
        size_t b0 = (size_t)(blk & 127) * 16384;
#pragma unroll
        for (int i = 0; i < 4; ++i) {
            size_t e = b0 + (size_t)(i * 256 + tid) * 16;
            float4 x0 = *(const float4*)(src + e);
            float4 x1 = *(const float4*)(src + e + 4);
            float4 x2 = *(const float4*)(src + e + 8);
            float4 x3 = *(const float4*)(src + e + 12);
            *(uint4*)(dst + e) = pack4(x0, x1);
            *(uint4*)(dst + e + 8) = pack4(x2, x3);
        }
    } else {
        // sT stride 70 (35 dwords == 3 mod 32): conflict-free writes, ~2-way reads
        __shared__ unsigned short sT[64 * 70];
        __shared__ float sRed[4 * 64];
        const int vb = blk - 256;
        const int comp = vb & 1, mt = (vb >> 1) & 15, bh = vb >> 5;
        const int m0 = mt * 64;
        const float* src = (comp ? Vi : Vr) + (size_t)bh * 65536 + (size_t)m0 * 64;
        unsigned short* dstA = (comp ? VtI : VtR) + (size_t)bh * 65536;
#pragma unroll
        for (int i = 0; i < 4; ++i) {
            int e = i * 256 + tid;
            int m = e >> 4, d4 = (e & 15) * 4;
            float4 x = *(const float4*)(src + (size_t)m * 64 + d4);
            *(uint2*)&sT[m * 70 + d4] = make_uint2(pk2(x.x, x.y), pk2(x.z, x.w));
        }
        {
            int d = tid & 63, grp = tid >> 6;
            float s = 0.0f;
#pragma unroll
            for (int k = 0; k < 16; ++k) s += src[(size_t)(grp * 16 + k) * 64 + d];
            sRed[grp * 64 + d] = s;
        }
        __syncthreads();
        {
            int d = tid >> 2, ms = (tid & 3) * 16;
            unsigned short v[16];
#pragma unroll
            for (int k = 0; k < 16; ++k) v[k] = sT[(ms + k) * 70 + d];
            unsigned short* dst = dstA + (size_t)d * 1024 + m0 + ms;
            *(uint4*)dst = make_uint4((unsigned)v[0] | ((unsigned)v[1] << 16),
                                      (unsigned)v[2] | ((unsigned)v[3] << 16),
                                      (unsigned)v[4] | ((unsigned)v[5] << 16),
                                      (unsigned)v[6] | ((unsigned)v[7] << 16));
            *(uint4*)(dst + 8) = make_uint4((unsigned)v[8] | ((unsigned)v[9] << 16),
                                            (unsigned)v[10] | ((unsigned)v[11] << 16),
                                            (unsigned)v[12] | ((unsigned)v[13] << 16),
                                            (unsigned)v[14] | ((unsigned)v[15] << 16));
        }
        if (tid < 64)
            ws[WS_SVP + comp * 32768 + bh * 1024 + tid * 16 + mt] =
                sRed[tid] + sRed[64 + tid] + sRed[128 + tid] + sRed[192 + tid];
    }
}

// ---------------- staging / fragment helpers ----------------
__device__ __forceinline__ void stage64s(const unsigned short* g0, int stride,
                                         unsigned short* lds, int w, int lane) {
#pragma unroll
    for (int i = 0; i < 2; ++i) {
        int c = w * 2 + i;
        int lrow = c * 8 + (lane >> 3);
        int lg = (lane & 7) ^ (lrow & 7);
        const unsigned short* src = g0 + (size_t)lrow * stride + lg * 8;
        __builtin_amdgcn_global_load_lds(
            (const __attribute__((address_space(1))) void*)src,
            (__attribute__((address_space(3))) void*)(lds + c * 512), 16, 0, 0);
    }
}
__device__ __forceinline__ bf16x8 ldfrag(const unsigned short* b, int row, int g) {
    return *(const bf16x8*)&b[row * 64 + ((g ^ (row & 7)) << 3)];
}

// ---------------- wide attention: 512 thr, q-tile 128, staging halved ----------------
// Hypothesis under test: the ~50% idle at round 5 is staging-throughput
// (64 KB/CU/iter of K/V re-staged by every q-tile block). Doubling the
// q-rows per block halves total staging bytes (256 MB -> 128 MB) at the
// same per-wave code. Waves 0-3 DMA K (dbuf, end-wait), waves 4-7 DMA V
// (single, mid-wait) -- round-1 split-wait semantics preserved.
constexpr int OFF_DEN = 0;                        // f32 [4][128]      2048 B
constexpr int OFF_K0  = 2048;                     // u16 [2][4096]    16384 B
constexpr int OFF_K1  = OFF_K0 + 16384;
constexpr int OFF_V0  = OFF_K1 + 16384;           // u16 [4096]        8192 B
constexpr int OFF_V1  = OFF_V0 + 8192;
constexpr int OFF_E   = OFF_V1 + 8192;            // u16 [128*64]     16384 B
constexpr int OFF_MG  = OFF_E + 16384;
constexpr int OFF_AMB = OFF_MG + 16384;           // u16 [4*1032]      8256 B
constexpr int SMEM_BYTES = OFF_AMB + 8256;        // = 92224

__global__ __launch_bounds__(ADIM, 2)
void attn_kernel_w(const float* __restrict__ Qr, const float* __restrict__ Qi,
                   const float* __restrict__ ws, float* __restrict__ out, float4 invn) {
    extern __shared__ char smem[];
    float* sDen = (float*)(smem + OFF_DEN);
    unsigned short* sK0 = (unsigned short*)(smem + OFF_K0);   // [2][4096]
    unsigned short* sK1 = (unsigned short*)(smem + OFF_K1);
    unsigned short* sV0 = (unsigned short*)(smem + OFF_V0);
    unsigned short* sV1 = (unsigned short*)(smem + OFF_V1);
    unsigned short* sE  = (unsigned short*)(smem + OFF_E);    // stride 64, 128 rows
    unsigned short* sMg = (unsigned short*)(smem + OFF_MG);
    unsigned short* sAmb = (unsigned short*)(smem + OFF_AMB); // stride 1032

    const int tid = threadIdx.x;
    const int lane = tid & 63;
    const int w = tid >> 6;                     // 0..7
    const int lo16 = lane & 15;
    const int quad = lane >> 4;
    const int blk = blockIdx.x;                 // 256 blocks
    const int bh = (blk & 7) * 4 + (blk >> 6);  // XCD-clustered: 4 bh per XCD
    const int qt = (blk >> 3) & 7;
    const int l0 = qt * 128;
    const size_t base = (size_t)bh * (L_ * D_);

    const unsigned short* gKr = (const unsigned short*)(ws + WS_KBR) + (size_t)bh * 65536;
    const unsigned short* gKi = (const unsigned short*)(ws + WS_KBI) + (size_t)bh * 65536;
    const unsigned short* gVr = (const unsigned short*)(ws + WS_VTR) + (size_t)bh * 65536;
    const unsigned short* gVi = (const unsigned short*)(ws + WS_VTI) + (size_t)bh * 65536;

    // waves 0-3 stage K(0) (overlaps amb trig + Q packing)
    if (w < 4) {
        stage64s(gKr, 64, sK0, w, lane);
        stage64s(gKi, 64, sK1, w, lane);
    }

    // amb table (a/8 bf16)
    for (int e = tid; e < 4096; e += ADIM) {
        int s = e >> 10, l = e & 1023;
        sAmb[s * 1032 + l] = f2b(a_val(s, l, invn) * 0.125f);
    }

    // Q fragments
    bf16x8 fQr0, fQr1, fQi0, fQi1, fnQi0, fnQi1;
    {
        const int ql = l0 + w * 16 + lo16;
        const float* qr = Qr + base + (size_t)ql * 64;
        const float* qi = Qi + base + (size_t)ql * 64;
        float4 a0 = *(const float4*)(qr + quad * 8);
        float4 a1 = *(const float4*)(qr + quad * 8 + 4);
        float4 b0 = *(const float4*)(qr + 32 + quad * 8);
        float4 b1 = *(const float4*)(qr + 32 + quad * 8 + 4);
        *(uint4*)&fQr0 = pack4(a0, a1);
        *(uint4*)&fQr1 = pack4(b0, b1);
        a0 = *(const float4*)(qi + quad * 8);
        a1 = *(const float4*)(qi + quad * 8 + 4);
        b0 = *(const float4*)(qi + 32 + quad * 8);
        b1 = *(const float4*)(qi + 32 + quad * 8 + 4);
        *(uint4*)&fQi0 = pack4(a0, a1);
        *(uint4*)&fQi1 = pack4(b0, b1);
        uint4 t0 = *(uint4*)&fQi0, t1 = *(uint4*)&fQi1;
        t0.x ^= 0x80008000u; t0.y ^= 0x80008000u; t0.z ^= 0x80008000u; t0.w ^= 0x80008000u;
        t1.x ^= 0x80008000u; t1.y ^= 0x80008000u; t1.z ^= 0x80008000u; t1.w ^= 0x80008000u;
        *(uint4*)&fnQi0 = t0; *(uint4*)&fnQi1 = t1;
    }

    __syncthreads();   // full drain: K(0) + sAmb visible

    bf16x8 uf1a = (bf16x8){0, 0, 0, 0, 0, 0, 0, 0};
    uf1a[0] = (short)f2b(b2f(sAmb[quad * 1032 + (l0 + w * 16 + lo16)]) *
                         (1.0f / 128.0f));

    f32x4 accM1 = (f32x4){0.f, 0.f, 0.f, 0.f};
    f32x4 aOutR[4], aOutI[4];
#pragma unroll
    for (int dt = 0; dt < 4; ++dt) {
        aOutR[dt] = (f32x4){0.f, 0.f, 0.f, 0.f};
        aOutI[dt] = (f32x4){0.f, 0.f, 0.f, 0.f};
    }

#pragma unroll 1
    for (int mt = 0; mt < 16; ++mt) {
        const int m0 = mt * 64;
        const int cur = mt & 1;
        // waves 4-7: V(mt), waited at mid barrier. waves 0-3: K(mt+1) prefetch.
        if (w >= 4) {
            stage64s(gVr + m0, 1024, sV0, w - 4, lane);
            stage64s(gVi + m0, 1024, sV1, w - 4, lane);
        } else if (mt < 15) {
            stage64s(gKr + (size_t)(m0 + 64) * 64, 64, sK0 + (cur ^ 1) * 4096, w, lane);
            stage64s(gKi + (size_t)(m0 + 64) * 64, 64, sK1 + (cur ^ 1) * 4096, w, lane);
        }
        const unsigned short* cK0 = sK0 + cur * 4096;
        const unsigned short* cK1 = sK1 + cur * 4096;

#pragma unroll
        for (int ct = 0; ct < 4; ++ct) {
            const int mrow = ct * 16 + lo16;
            bf16x8 kr0 = ldfrag(cK0, mrow, quad), kr1 = ldfrag(cK0, mrow, quad + 4);
            bf16x8 ki0 = ldfrag(cK1, mrow, quad), ki1 = ldfrag(cK1, mrow, quad + 4);
            f32x4 aR = (f32x4){0.f, 0.f, 0.f, 0.f};
            f32x4 aI = (f32x4){0.f, 0.f, 0.f, 0.f};
            __builtin_amdgcn_s_setprio(1);
            aR = MFMA(kr0, fQr0, aR);  aR = MFMA(kr1, fQr1, aR);   // S^T = K·Q^T
            aR = MFMA(ki0, fnQi0, aR); aR = MFMA(ki1, fnQi1, aR);
            aI = MFMA(ki0, fQr0, aI);  aI = MFMA(ki1, fQr1, aI);
            aI = MFMA(kr0, fQi0, aI);  aI = MFMA(kr1, fQi1, aI);
            __builtin_amdgcn_s_setprio(0);
            float mg0 = vsqrt(fmaf(aR[0], aR[0], aI[0] * aI[0]));
            float mg1 = vsqrt(fmaf(aR[1], aR[1], aI[1] * aI[1]));
            float mg2 = vsqrt(fmaf(aR[2], aR[2], aI[2] * aI[2]));
            float mg3 = vsqrt(fmaf(aR[3], aR[3], aI[3] * aI[3]));
            bf16x8 bf1 = (bf16x8){0, 0, 0, 0, 0, 0, 0, 0};
            bf1[0] = (short)sAmb[quad * 1032 + m0 + ct * 16 + lo16];
            f32x4 z = (f32x4){0.f, 0.f, 0.f, 0.f};
            f32x4 a1 = MFMA(bf1, uf1a, z);
            float p0 = mg0 * a1[0], p1 = mg1 * a1[1];
            float p2 = mg2 * a1[2], p3 = mg3 * a1[3];
            int l = w * 16 + lo16;
            int gph = (ct * 2 + (quad >> 1)) ^ (l & 7);
            *(uint2*)&sE[l * 64 + gph * 8 + (quad & 1) * 4] =
                make_uint2(cvtpk(p0, p1), cvtpk(p2, p3));
            *(uint2*)&sMg[l * 64 + gph * 8 + (quad & 1) * 4] =
                make_uint2(cvtpk(mg0, mg1), cvtpk(mg2, mg3));
        }
        // M1 matvec (same-wave slab round-trip)
        {
            bf16x8 mf0 = ldfrag(sMg, w * 16 + lo16, quad);
            bf16x8 mf1 = ldfrag(sMg, w * 16 + lo16, quad + 4);
            bf16x8 b0 = (bf16x8){0, 0, 0, 0, 0, 0, 0, 0};
            bf16x8 b1 = (bf16x8){0, 0, 0, 0, 0, 0, 0, 0};
            if (lo16 < 4) {
                b0 = *(const bf16x8*)&sAmb[lo16 * 1032 + m0 + quad * 8];
                b1 = *(const bf16x8*)&sAmb[lo16 * 1032 + m0 + 32 + quad * 8];
            }
            accM1 = MFMA(mf0, b0, accM1);
            accM1 = MFMA(mf1, b1, accM1);
        }
        // mid: V-stagers drain their own V(mt); barrier publishes sV
        if (w >= 4) asm volatile("s_waitcnt vmcnt(0)" ::: "memory");
        __builtin_amdgcn_s_barrier();
        // PV
        {
            bf16x8 pa0 = ldfrag(sE, w * 16 + lo16, quad);
            bf16x8 pa1 = ldfrag(sE, w * 16 + lo16, quad + 4);
            __builtin_amdgcn_s_setprio(1);
#pragma unroll
            for (int dt = 0; dt < 4; ++dt) {
                int dr = dt * 16 + lo16;
                bf16x8 vr0 = ldfrag(sV0, dr, quad), vr1 = ldfrag(sV0, dr, quad + 4);
                bf16x8 vi0 = ldfrag(sV1, dr, quad), vi1 = ldfrag(sV1, dr, quad + 4);
                aOutR[dt] = MFMA(pa0, vr0, aOutR[dt]);
                aOutR[dt] = MFMA(pa1, vr1, aOutR[dt]);
                aOutI[dt] = MFMA(pa0, vi0, aOutI[dt]);
                aOutI[dt] = MFMA(pa1, vi1, aOutI[dt]);
            }
            __builtin_amdgcn_s_setprio(0);
        }
        // end: K-stagers drain K(mt+1); barrier -> next iter may read it
        if (w < 4) asm volatile("s_waitcnt vmcnt(0)" ::: "memory");
        __builtin_amdgcn_s_barrier();
    }

    // exact denominators
    if (lo16 < 4) {
#pragma unroll
        for (int reg = 0; reg < 4; ++reg) {
            int r = w * 16 + quad * 4 + reg;
            float alv = b2f(sAmb[lo16 * 1032 + (l0 + r)]) * 8.0f;
            sDen[lo16 * 128 + r] = 1.0f / (1024.0f + alv * accM1[reg]);
        }
    }
    float cden[4];
#pragma unroll
    for (int reg = 0; reg < 4; ++reg) {
        int r = w * 16 + quad * 4 + reg;   // same-wave LDS read
        cden[reg] = sDen[r] + sDen[128 + r] + sDen[256 + r] + sDen[384 + r];
    }

    // expert eC
    const float cE = rsqrtf(2048.0f) * rsqrtf(24.0f);
    float eRr[4], eRi[4];
#pragma unroll
    for (int reg = 0; reg < 4; ++reg) {
        int lrow = l0 + w * 16 + quad * 4 + reg;
        float tl = (2.0f * PI_F / (float)(LMAX_ - 1)) * (float)lrow;
        float s1, c1;
        __sincosf(0.1f * tl, &s1, &c1);
        const float W[10] = {1.f, 2.f, 3.f, 3.f, 3.f, 3.f, 3.f, 3.f, 2.f, 1.f};
        float cr = c1, ci = s1;
        float er = W[0] * cr, ei = W[0] * ci;
#pragma unroll
        for (int k = 1; k < 10; ++k) {
            float nr = cr * c1 - ci * s1;
            float ni = cr * s1 + ci * c1;
            cr = nr; ci = ni;
            er = fmaf(W[k], cr, er);
            ei = fmaf(W[k], ci, ei);
        }
        eRr[reg] = er * cE;
        eRi[reg] = ei * cE;
    }

    const size_t ooff = (size_t)BH_ * L_ * D_;
#pragma unroll
    for (int dt = 0; dt < 4; ++dt) {
        int d = dt * 16 + lo16;
        const float* svp = ws + WS_SVP + bh * 1024 + (size_t)d * 16;
        float4 r0 = *(const float4*)(svp);
        float4 r1 = *(const float4*)(svp + 4);
        float4 r2 = *(const float4*)(svp + 8);
        float4 r3 = *(const float4*)(svp + 12);
        float svr = (r0.x + r0.y + r0.z + r0.w) + (r1.x + r1.y + r1.z + r1.w) +
                    (r2.x + r2.y + r2.z + r2.w) + (r3.x + r3.y + r3.z + r3.w);
        const float* svq = svp + 32768;
        r0 = *(const float4*)(svq);
        r1 = *(const float4*)(svq + 4);
        r2 = *(const float4*)(svq + 8);
        r3 = *(const float4*)(svq + 12);
        float svi = (r0.x + r0.y + r0.z + r0.w) + (r1.x + r1.y + r1.z + r1.w) +
                    (r2.x + r2.y + r2.z + r2.w) + (r3.x + r3.y + r3.z + r3.w);
        float sp, cp;
        __sincosf((2.0f * PI_F / 64.0f) * (float)d, &sp, &cp);
#pragma unroll
        for (int reg = 0; reg < 4; ++reg) {
            int lrow = l0 + w * 16 + quad * 4 + reg;
            float numR = fmaf(cden[reg], svr, aOutR[dt][reg]) * 0.5f;
            float numI = fmaf(cden[reg], svi, aOutI[dt][reg]) * 0.5f;
            float epr = cp * eRr[reg] - sp * eRi[reg];
            float epi = sp * eRr[reg] + cp * eRi[reg];
            size_t o = base + (size_t)lrow * 64 + d;
            out[o] = numR * epr - numI * epi;
            out[o + ooff] = numR * epi + numI * epr;
        }
    }
}

// ---------------- fallback: round-5 256-thr attention (verbatim) ----------------
__global__ __launch_bounds__(BDIM, 2)
void attn_kernel(const float* __restrict__ Qr, const float* __restrict__ Qi,
                 const float* __restrict__ ws, float* __restrict__ out, float4 invn) {
    __shared__ unsigned short sK0[2][4096], sK1[2][4096];
    __shared__ unsigned short sV0[4096], sV1[4096];
    __shared__ unsigned short sE[4096];
    __shared__ unsigned short sMg[4096];
    __shared__ unsigned short sAmb[4 * 1032];
    __shared__ float sDen[4 * 64];

    const int tid = threadIdx.x;
    const int lane = tid & 63;
    const int w = tid >> 6;
    const int lo16 = lane & 15;
    const int quad = lane >> 4;
    const int blk = blockIdx.x;
    const int bh = (blk & 7) * 4 + (blk >> 7);
    const int qt = (blk >> 3) & 15;
    const int l0 = qt * 64;
    const size_t base = (size_t)bh * (L_ * D_);

    const unsigned short* gKr = (const unsigned short*)(ws + WS_KBR) + (size_t)bh * 65536;
    const unsigned short* gKi = (const unsigned short*)(ws + WS_KBI) + (size_t)bh * 65536;
    const unsigned short* gVr = (const unsigned short*)(ws + WS_VTR) + (size_t)bh * 65536;
    const unsigned short* gVi = (const unsigned short*)(ws + WS_VTI) + (size_t)bh * 65536;

    stage64s(gKr, 64, sK0[0], w, lane);
    stage64s(gKi, 64, sK1[0], w, lane);

    for (int e = tid; e < 4096; e += BDIM) {
        int s = e >> 10, l = e & 1023;
        sAmb[s * 1032 + l] = f2b(a_val(s, l, invn) * 0.125f);
    }

    bf16x8 fQr0, fQr1, fQi0, fQi1, fnQi0, fnQi1;
    {
        const int ql = l0 + w * 16 + lo16;
        const float* qr = Qr + base + (size_t)ql * 64;
        const float* qi = Qi + base + (size_t)ql * 64;
        float4 a0 = *(const float4*)(qr + quad * 8);
        float4 a1 = *(const float4*)(qr + quad * 8 + 4);
        float4 b0 = *(const float4*)(qr + 32 + quad * 8);
        float4 b1 = *(const float4*)(qr + 32 + quad * 8 + 4);
        *(uint4*)&fQr0 = pack4(a0, a1);
        *(uint4*)&fQr1 = pack4(b0, b1);
        a0 = *(const float4*)(qi + quad * 8);
        a1 = *(const float4*)(qi + quad * 8 + 4);
        b0 = *(const float4*)(qi + 32 + quad * 8);
        b1 = *(const float4*)(qi + 32 + quad * 8 + 4);
        *(uint4*)&fQi0 = pack4(a0, a1);
        *(uint4*)&fQi1 = pack4(b0, b1);
        uint4 t0 = *(uint4*)&fQi0, t1 = *(uint4*)&fQi1;
        t0.x ^= 0x80008000u; t0.y ^= 0x80008000u; t0.z ^= 0x80008000u; t0.w ^= 0x80008000u;
        t1.x ^= 0x80008000u; t1.y ^= 0x80008000u; t1.z ^= 0x80008000u; t1.w ^= 0x80008000u;
        *(uint4*)&fnQi0 = t0; *(uint4*)&fnQi1 = t1;
    }

    __syncthreads();

    bf16x8 uf1a = (bf16x8){0, 0, 0, 0, 0, 0, 0, 0};
    uf1a[0] = (short)f2b(b2f(sAmb[quad * 1032 + (l0 + w * 16 + lo16)]) *
                         (1.0f / 128.0f));

    f32x4 accM1 = (f32x4){0.f, 0.f, 0.f, 0.f};
    f32x4 aOutR[4], aOutI[4];
#pragma unroll
    for (int dt = 0; dt < 4; ++dt) {
        aOutR[dt] = (f32x4){0.f, 0.f, 0.f, 0.f};
        aOutI[dt] = (f32x4){0.f, 0.f, 0.f, 0.f};
    }

#pragma unroll 1
    for (int mt = 0; mt < 16; ++mt) {
        const int m0 = mt * 64;
        const int cur = mt & 1;
        stage64s(gVr + m0, 1024, sV0, w, lane);
        stage64s(gVi + m0, 1024, sV1, w, lane);
        if (mt < 15) {
            stage64s(gKr + (size_t)(m0 + 64) * 64, 64, sK0[cur ^ 1], w, lane);
            stage64s(gKi + (size_t)(m0 + 64) * 64, 64, sK1[cur ^ 1], w, lane);
        }
        const unsigned short* cK0 = sK0[cur];
        const unsigned short* cK1 = sK1[cur];

#pragma unroll
        for (int ct = 0; ct < 4; ++ct) {
            const int mrow = ct * 16 + lo16;
            bf16x8 kr0 = ldfrag(cK0, mrow, quad), kr1 = ldfrag(cK0, mrow, quad + 4);
            bf16x8 ki0 = ldfrag(cK1, mrow, quad), ki1 = ldfrag(cK1, mrow, quad + 4);
            f32x4 aR = (f32x4){0.f, 0.f, 0.f, 0.f};
            f32x4 aI = (f32x4){0.f, 0.f, 0.f, 0.f};
            __builtin_amdgcn_s_setprio(1);
            aR = MFMA(kr0, fQr0, aR);  aR = MFMA(kr1, fQr1, aR);
            aR = MFMA(ki0, fnQi0, aR); aR = MFMA(ki1, fnQi1, aR);
            aI = MFMA(ki0, fQr0, aI);  aI = MFMA(ki1, fQr1, aI);
            aI = MFMA(kr0, fQi0, aI);  aI = MFMA(kr1, fQi1, aI);
            __builtin_amdgcn_s_setprio(0);
            float mg0 = vsqrt(fmaf(aR[0], aR[0], aI[0] * aI[0]));
            float mg1 = vsqrt(fmaf(aR[1], aR[1], aI[1] * aI[1]));
            float mg2 = vsqrt(fmaf(aR[2], aR[2], aI[2] * aI[2]));
            float mg3 = vsqrt(fmaf(aR[3], aR[3], aI[3] * aI[3]));
            bf16x8 bf1 = (bf16x8){0, 0, 0, 0, 0, 0, 0, 0};
            bf1[0] = (short)sAmb[quad * 1032 + m0 + ct * 16 + lo16];
            f32x4 z = (f32x4){0.f, 0.f, 0.f, 0.f};
            f32x4 a1 = MFMA(bf1, uf1a, z);
            float p0 = mg0 * a1[0], p1 = mg1 * a1[1];
            float p2 = mg2 * a1[2], p3 = mg3 * a1[3];
            int l = w * 16 + lo16;
            int gph = (ct * 2 + (quad >> 1)) ^ (l & 7);
            *(uint2*)&sE[l * 64 + gph * 8 + (quad & 1) * 4] =
                make_uint2(cvtpk(p0, p1), cvtpk(p2, p3));
            *(uint2*)&sMg[l * 64 + gph * 8 + (quad & 1) * 4] =
                make_uint2(cvtpk(mg0, mg1), cvtpk(mg2, mg3));
        }
        {
            bf16x8 mf0 = ldfrag(sMg, w * 16 + lo16, quad);
            bf16x8 mf1 = ldfrag(sMg, w * 16 + lo16, quad + 4);
            bf16x8 b0 = (bf16x8){0, 0, 0, 0, 0, 0, 0, 0};
            bf16x8 b1 = (bf16x8){0, 0, 0, 0, 0, 0, 0, 0};
            if (lo16 < 4) {
                b0 = *(const bf16x8*)&sAmb[lo16 * 1032 + m0 + quad * 8];
                b1 = *(const bf16x8*)&sAmb[lo16 * 1032 + m0 + 32 + quad * 8];
            }
            accM1 = MFMA(mf0, b0, accM1);
            accM1 = MFMA(mf1, b1, accM1);
        }
        if (mt < 15) {
            asm volatile("s_waitcnt vmcnt(4)" ::: "memory");
        } else {
            asm volatile("s_waitcnt vmcnt(0)" ::: "memory");
        }
        __builtin_amdgcn_s_barrier();
        {
            bf16x8 pa0 = ldfrag(sE, w * 16 + lo16, quad);
            bf16x8 pa1 = ldfrag(sE, w * 16 + lo16, quad + 4);
            __builtin_amdgcn_s_setprio(1);
#pragma unroll
            for (int dt = 0; dt < 4; ++dt) {
                int dr = dt * 16 + lo16;
                bf16x8 vr0 = ldfrag(sV0, dr, quad), vr1 = ldfrag(sV0, dr, quad + 4);
                bf16x8 vi0 = ldfrag(sV1, dr, quad), vi1 = ldfrag(sV1, dr, quad + 4);
                aOutR[dt] = MFMA(pa0, vr0, aOutR[dt]);
                aOutR[dt] = MFMA(pa1, vr1, aOutR[dt]);
                aOutI[dt] = MFMA(pa0, vi0, aOutI[dt]);
                aOutI[dt] = MFMA(pa1, vi1, aOutI[dt]);
            }
            __builtin_amdgcn_s_setprio(0);
        }
        asm volatile("s_waitcnt vmcnt(0)" ::: "memory");
        __builtin_amdgcn_s_barrier();
    }

    if (lo16 < 4) {
#pragma unroll
        for (int reg = 0; reg < 4; ++reg) {
            int r = w * 16 + quad * 4 + reg;
            float alv = b2f(sAmb[lo16 * 1032 + (l0 + r)]) * 8.0f;
            sDen[lo16 * 64 + r] = 1.0f / (1024.0f + alv * accM1[reg]);
        }
    }
    float cden[4];
#pragma unroll
    for (int reg = 0; reg < 4; ++reg) {
        int r = w * 16 + quad * 4 + reg;
        cden[reg] = sDen[r] + sDen[64 + r] + sDen[128 + r] + sDen[192 + r];
    }

    const float cE = rsqrtf(2048.0f) * rsqrtf(24.0f);
    float eRr[4], eRi[4];
#pragma unroll
    for (int reg = 0; reg < 4; ++reg) {
        int lrow = l0 + w * 16 + quad * 4 + reg;
        float tl = (2.0f * PI_F / (float)(LMAX_ - 1)) * (float)lrow;
        float s1, c1;
        __sincosf(0.1f * tl, &s1, &c1);
        const float W[10] = {1.f, 2.f, 3.f, 3.f, 3.f, 3.f, 3.f, 3.f, 2.f, 1.f};
        float cr = c1, ci = s1;
        float er = W[0] * cr, ei = W[0] * ci;
#pragma unroll
        for (int k = 1; k < 10; ++k) {
            float nr = cr * c1 - ci * s1;
            float ni = cr * s1 + ci * c1;
            cr = nr; ci = ni;
            er = fmaf(W[k], cr, er);
            ei = fmaf(W[k], ci, ei);
        }
        eRr[reg] = er * cE;
        eRi[reg] = ei * cE;
    }

    const size_t ooff = (size_t)BH_ * L_ * D_;
#pragma unroll
    for (int dt = 0; dt < 4; ++dt) {
        int d = dt * 16 + lo16;
        const float* svp = ws + WS_SVP + bh * 1024 + (size_t)d * 16;
        float4 r0 = *(const float4*)(svp);
        float4 r1 = *(const float4*)(svp + 4);
        float4 r2 = *(const float4*)(svp + 8);
        float4 r3 = *(const float4*)(svp + 12);
        float svr = (r0.x + r0.y + r0.z + r0.w) + (r1.x + r1.y + r1.z + r1.w) +
                    (r2.x + r2.y + r2.z + r2.w) + (r3.x + r3.y + r3.z + r3.w);
        const float* svq = svp + 32768;
        r0 = *(const float4*)(svq);
        r1 = *(const float4*)(svq + 4);
        r2 = *(const float4*)(svq + 8);
        r3 = *(const float4*)(svq + 12);
        float svi = (r0.x + r0.y + r0.z + r0.w) + (r1.x + r1.y + r1.z + r1.w) +
                    (r2.x + r2.y + r2.z + r2.w) + (r3.x + r3.y + r3.z + r3.w);
        float sp, cp;
        __sincosf((2.0f * PI_F / 64.0f) * (float)d, &sp, &cp);
#pragma unroll
        for (int reg = 0; reg < 4; ++reg) {
            int lrow = l0 + w * 16 + quad * 4 + reg;
            float numR = fmaf(cden[reg], svr, aOutR[dt][reg]) * 0.5f;
            float numI = fmaf(cden[reg], svi, aOutI[dt][reg]) * 0.5f;
            float epr = cp * eRr[reg] - sp * eRi[reg];
            float epi = sp * eRr[reg] + cp * eRi[reg];
            size_t o = base + (size_t)lrow * 64 + d;
            out[o] = numR * epr - numI * epi;
            out[o + ooff] = numR * epi + numI * epr;
        }
    }
}

extern "C" void kernel_launch(void* const* d_in, const int* in_sizes, int n_in,
                              void* d_out, int out_size, void* d_ws, size_t ws_size,
                              hipStream_t stream) {
    const float* Qr = (const float*)d_in[0];
    const float* Qi = (const float*)d_in[1];
    const float* Kr = (const float*)d_in[2];
    const float* Ki = (const float*)d_in[3];
    const float* Vr = (const float*)d_in[4];
    const float* Vi = (const float*)d_in[5];
    float* ws = (float*)d_ws;
    float* out = (float*)d_out;

    const double fr[4] = {1.0, 0.5, 0.25, 0.1};
    float inv[4];
    for (int s = 0; s < 4; ++s) {
        double a = 2.0 * 3.14159265358979323846 * fr[s] / (double)(LMAX_ - 1);
        double S = 3.0 * LMAX_;
        const double mul[3] = {1.0, 0.5, 1.5};
        for (int k = 0; k < 3; ++k) {
            double x = a * mul[k];
            S += 2.0 * (cos(x * 1023.5) * sin(x * 1024.0) / sin(x * 0.5));
        }
        inv[s] = (float)(1.0 / sqrt(S));
    }
    float4 invn = make_float4(inv[0], inv[1], inv[2], inv[3]);

    prep_kernel<<<1280, BDIM, 0, stream>>>(Kr, Ki, Vr, Vi, ws);

    // wide attn needs 92,224 B dynamic LDS (>64K static limit)
    static int wideOK = -1;
    if (wideOK < 0) {
        hipError_t e = hipFuncSetAttribute(
            reinterpret_cast<const void*>(attn_kernel_w),
            hipFuncAttributeMaxDynamicSharedMemorySize, SMEM_BYTES);
        wideOK = (e == hipSuccess) ? 1 : 0;
    }
    if (wideOK)
        attn_kernel_w<<<256, ADIM, SMEM_BYTES, stream>>>(Qr, Qi, ws, out, invn);
    else
        attn_kernel<<<512, BDIM, 0, stream>>>(Qr, Qi, ws, out, invn);
}